// Round 7
// baseline (147.737 us; speedup 1.0000x reference)
//
#include <hip/hip_runtime.h>
#include <math.h>

#define BB 128
#define HH 768
#define KQ 32768
#define PCAP 18432  // max positives per row staged in LDS
#define NB 4096     // histogram bins
#define CCAP 512    // candidate cap per target bin

constexpr float TINV = 1.0f / 0.07f;

typedef __attribute__((ext_vector_type(8))) short short8;
typedef __attribute__((ext_vector_type(4))) float f32x4;

__device__ __forceinline__ unsigned short f2bf(float f) {
  unsigned u = __float_as_uint(f);
  unsigned r = u + 0x7FFFu + ((u >> 16) & 1u);  // RNE
  return (unsigned short)(r >> 16);
}
__device__ __forceinline__ unsigned f2key(float f) {
  unsigned u = __float_as_uint(f);
  return u ^ (unsigned)(((int)u >> 31) | 0x80000000);
}
__device__ __forceinline__ float key2f(unsigned k) {
  unsigned u = (k & 0x80000000u) ? (k & 0x7FFFFFFFu) : ~k;
  return __uint_as_float(u);
}
__device__ __forceinline__ unsigned long long shfl_down_u64(unsigned long long v, int o) {
  unsigned lo = (unsigned)v, hi = (unsigned)(v >> 32);
  lo = __shfl_down(lo, o);
  hi = __shfl_down(hi, o);
  return ((unsigned long long)hi << 32) | lo;
}

// C = tanh(A @ W{0,1} + b{0,1}); z picks head. BM=BN=32, BK=32, 256 thr.
__global__ __launch_bounds__(256) void dense_pair(
    const float* __restrict__ A, const float* __restrict__ W0,
    const float* __restrict__ b0, float* __restrict__ C0,
    const float* __restrict__ W1, const float* __restrict__ b1,
    float* __restrict__ C1) {
  const float* W = blockIdx.z ? W1 : W0;
  const float* bias = blockIdx.z ? b1 : b0;
  float* Cout = blockIdx.z ? C1 : C0;
  __shared__ float As[32][33];
  __shared__ float Ws[32][36];
  const int n0 = blockIdx.x * 32;
  const int m0 = blockIdx.y * 32;
  const int tid = threadIdx.x;
  const int tn = tid & 15, tm = tid >> 4;
  const int r = tid >> 3, c = (tid & 7) << 2;
  float acc[2][2] = {};
  for (int k0 = 0; k0 < HH; k0 += 32) {
    const float4 a4 = *reinterpret_cast<const float4*>(A + (size_t)(m0 + r) * HH + k0 + c);
    As[c + 0][r] = a4.x; As[c + 1][r] = a4.y; As[c + 2][r] = a4.z; As[c + 3][r] = a4.w;
    const float4 w4 = *reinterpret_cast<const float4*>(W + (size_t)(k0 + r) * HH + n0 + c);
    *reinterpret_cast<float4*>(&Ws[r][c]) = w4;
    __syncthreads();
#pragma unroll
    for (int kk = 0; kk < 32; ++kk) {
      const float a0 = As[kk][tm * 2], a1 = As[kk][tm * 2 + 1];
      const float w0 = Ws[kk][tn * 2], w1 = Ws[kk][tn * 2 + 1];
      acc[0][0] = fmaf(a0, w0, acc[0][0]); acc[0][1] = fmaf(a0, w1, acc[0][1]);
      acc[1][0] = fmaf(a1, w0, acc[1][0]); acc[1][1] = fmaf(a1, w1, acc[1][1]);
    }
    __syncthreads();
  }
  const float b0v = bias[n0 + tn * 2], b1v = bias[n0 + tn * 2 + 1];
#pragma unroll
  for (int i = 0; i < 2; ++i) {
    float* dst = Cout + (size_t)(m0 + tm * 2 + i) * HH + n0 + tn * 2;
    dst[0] = tanhf(acc[i][0] + b0v);
    dst[1] = tanhf(acc[i][1] + b1v);
  }
}

// C = A @ W + b (no act). BM=BN=32, BK=32.
__global__ __launch_bounds__(256) void gemm_bias(
    const float* __restrict__ A, const float* __restrict__ W,
    const float* __restrict__ bias, float* __restrict__ Cout) {
  __shared__ float As[32][33];
  __shared__ float Ws[32][36];
  const int n0 = blockIdx.x * 32;
  const int m0 = blockIdx.y * 32;
  const int tid = threadIdx.x;
  const int tn = tid & 15, tm = tid >> 4;
  const int r = tid >> 3, c = (tid & 7) << 2;
  float acc[2][2] = {};
  for (int k0 = 0; k0 < HH; k0 += 32) {
    const float4 a4 = *reinterpret_cast<const float4*>(A + (size_t)(m0 + r) * HH + k0 + c);
    As[c + 0][r] = a4.x; As[c + 1][r] = a4.y; As[c + 2][r] = a4.z; As[c + 3][r] = a4.w;
    const float4 w4 = *reinterpret_cast<const float4*>(W + (size_t)(k0 + r) * HH + n0 + c);
    *reinterpret_cast<float4*>(&Ws[r][c]) = w4;
    __syncthreads();
#pragma unroll
    for (int kk = 0; kk < 32; ++kk) {
      const float a0 = As[kk][tm * 2], a1 = As[kk][tm * 2 + 1];
      const float w0 = Ws[kk][tn * 2], w1 = Ws[kk][tn * 2 + 1];
      acc[0][0] = fmaf(a0, w0, acc[0][0]); acc[0][1] = fmaf(a0, w1, acc[0][1]);
      acc[1][0] = fmaf(a1, w0, acc[1][0]); acc[1][1] = fmaf(a1, w1, acc[1][1]);
    }
    __syncthreads();
  }
  const float b0v = bias[n0 + tn * 2], b1v = bias[n0 + tn * 2 + 1];
#pragma unroll
  for (int i = 0; i < 2; ++i) {
    float* dst = Cout + (size_t)(m0 + tm * 2 + i) * HH + n0 + tn * 2;
    dst[0] = acc[i][0] + b0v;
    dst[1] = acc[i][1] + b1v;
  }
}

// cos GEMM: pure-bf16 MFMA, ZERO barriers, ZERO LDS.
// A fragments read straight from qh (192 KB, L2/L1-resident).
// B (fq) streams global->reg with 4-deep static prefetch.
// BM=128 (all batch) x BN=128 per block, 8 waves, grid=256.
__global__ __launch_bounds__(512, 1) void cos_gemm_mfma(
    const unsigned short* __restrict__ qh, const float* __restrict__ FQ,
    float* __restrict__ C) {
  const int tid = threadIdx.x;
  const int lane = tid & 63, wid = tid >> 6;
  const int q0 = blockIdx.x * 128;
  const int a_r = lane & 15;   // A row-within-16 / B col-within-16
  const int a_kq = lane >> 4;  // k-quarter
  // B: fq row = q0 + wid*16 + a_r, k cols = s*32 + a_kq*8 .. +8
  const float* __restrict__ bptr = FQ + (size_t)(q0 + wid * 16 + a_r) * HH + a_kq * 8;
  // A: qh row = m*16 + a_r, same k layout; 8 row-pointers, imm offset s*64B
  const unsigned short* ap[8];
#pragma unroll
  for (int m = 0; m < 8; ++m)
    ap[m] = qh + (size_t)(m * 16 + a_r) * HH + a_kq * 8;

  f32x4 acc[8];
#pragma unroll
  for (int m = 0; m < 8; ++m) acc[m] = (f32x4){0.f, 0.f, 0.f, 0.f};

  float4 bv[4][2];
#pragma unroll
  for (int p = 0; p < 3; ++p) {
    bv[p][0] = *reinterpret_cast<const float4*>(bptr + p * 32);
    bv[p][1] = *reinterpret_cast<const float4*>(bptr + p * 32 + 4);
  }

#pragma unroll
  for (int s = 0; s < 24; ++s) {
    if (s < 21) {
      bv[(s + 3) & 3][0] = *reinterpret_cast<const float4*>(bptr + (s + 3) * 32);
      bv[(s + 3) & 3][1] = *reinterpret_cast<const float4*>(bptr + (s + 3) * 32 + 4);
    }
    const float4 v0 = bv[s & 3][0], v1 = bv[s & 3][1];
    short8 bb;
    bb[0] = (short)f2bf(v0.x); bb[1] = (short)f2bf(v0.y);
    bb[2] = (short)f2bf(v0.z); bb[3] = (short)f2bf(v0.w);
    bb[4] = (short)f2bf(v1.x); bb[5] = (short)f2bf(v1.y);
    bb[6] = (short)f2bf(v1.z); bb[7] = (short)f2bf(v1.w);
#pragma unroll
    for (int m = 0; m < 8; ++m) {
      const short8 aa = *reinterpret_cast<const short8*>(ap[m] + s * 32);
      acc[m] = __builtin_amdgcn_mfma_f32_16x16x32_bf16(aa, bb, acc[m], 0, 0, 0);
    }
  }

  // C[row][col]: row = m*16 + a_kq*4 + r (batch), col = q0 + wid*16 + a_r
  const int ccol = q0 + wid * 16 + a_r;
#pragma unroll
  for (int m = 0; m < 8; ++m)
#pragma unroll
    for (int r = 0; r < 4; ++r)
      C[(size_t)(m * 16 + a_kq * 4 + r) * KQ + ccol] = acc[m][r];
}

// L2-normalize rows of Y and emit bf16.
__global__ __launch_bounds__(256) void l2norm_split(const float* __restrict__ Y,
                                                    unsigned short* __restrict__ qh) {
  const int b = blockIdx.x, tid = threadIdx.x;
  __shared__ float sh[4];
  __shared__ float snorm;
  float ss = 0.f;
  for (int h = tid; h < HH; h += 256) {
    const float v = Y[(size_t)b * HH + h];
    ss = fmaf(v, v, ss);
  }
  for (int o = 32; o; o >>= 1) ss += __shfl_down(ss, o);
  const int lane = tid & 63, wid = tid >> 6;
  if (lane == 0) sh[wid] = ss;
  __syncthreads();
  if (tid == 0) snorm = 1.0f / sqrtf(sh[0] + sh[1] + sh[2] + sh[3]);
  __syncthreads();
  const float rs = snorm;
  for (int h = tid; h < HH; h += 256)
    qh[(size_t)b * HH + h] = f2bf(Y[(size_t)b * HH + h] * rs);
}

__global__ __launch_bounds__(256) void cls_loss_kernel(
    const float* __restrict__ H1, const float* __restrict__ W2,
    const float* __restrict__ b2, const int* __restrict__ labels,
    float* __restrict__ out) {
  const int b = blockIdx.x, tid = threadIdx.x;
  __shared__ float sh0[4], sh1[4];
  float p0 = 0.f, p1 = 0.f;
  for (int h = tid; h < HH; h += 256) {
    const float v = H1[(size_t)b * HH + h];
    p0 = fmaf(v, W2[h * 2 + 0], p0);
    p1 = fmaf(v, W2[h * 2 + 1], p1);
  }
  for (int o = 32; o; o >>= 1) {
    p0 += __shfl_down(p0, o);
    p1 += __shfl_down(p1, o);
  }
  const int lane = tid & 63, wid = tid >> 6;
  if (lane == 0) { sh0[wid] = p0; sh1[wid] = p1; }
  __syncthreads();
  if (tid == 0) {
    const float l0 = sh0[0] + sh0[1] + sh0[2] + sh0[3] + b2[0];
    const float l1 = sh1[0] + sh1[1] + sh1[2] + sh1[3] + b2[1];
    const float mx = fmaxf(l0, l1), mn = fminf(l0, l1);
    const float lse = mx + log1pf(__expf(mn - mx));
    const float ce = lse - (labels[b] ? l1 : l0);
    atomicAdd(out, 0.9f * ce * (1.0f / 128.0f));
  }
}

// Also zeroes out[0] and builds qmask (bit=1 iff label_queue[k]==1).
__global__ __launch_bounds__(1024) void counts_kernel(const int* __restrict__ labels,
                                                      const int* __restrict__ lq,
                                                      int* __restrict__ m_out,
                                                      unsigned* __restrict__ qmask,
                                                      float* __restrict__ out) {
  const int tid = threadIdx.x;
  __shared__ int sh[16];
  __shared__ int has[2];
  unsigned mask = 0u;
  const int base = tid << 5;
#pragma unroll
  for (int j = 0; j < 32; ++j) mask |= (unsigned)(lq[base + j] != 0) << j;
  qmask[tid] = mask;
  int c = __popc(mask);
  for (int o = 32; o; o >>= 1) c += __shfl_down(c, o);
  const int lane = tid & 63, wid = tid >> 6;
  if (tid < 2) has[tid] = 0;
  __syncthreads();
  if (lane == 0) sh[wid] = c;
  if (tid < BB) has[labels[tid]] = 1;
  __syncthreads();
  if (tid == 0) {
    int n1 = 0;
    for (int w = 0; w < 16; ++w) n1 += sh[w];
    const int n0 = KQ - n1;
    int mm = 0x7fffffff;
    if (has[0] && n0 < mm) mm = n0;
    if (has[1] && n1 < mm) mm = n1;
    *m_out = mm;
    out[0] = 0.0f;
  }
}

// Pass A (row read + neg-lse + pos key compaction + pos min/max), then
// histogram radix-select for ranks {25, m-25, m}, then one gather pass.
__global__ __launch_bounds__(1024) void select_kernel(
    const float* __restrict__ Cm, const int* __restrict__ labels,
    const unsigned* __restrict__ qmask, const int* __restrict__ m_ptr,
    float* __restrict__ out) {
  const int b = blockIdx.x;
  const int tid = threadIdx.x;
  const int lane = tid & 63, wid = tid >> 6;
  const float* __restrict__ row = Cm + (size_t)b * KQ;
  const int lab = labels[b];
  const int m = *m_ptr;

  __shared__ __align__(16) unsigned poskeys[PCAP];
  __shared__ unsigned hist[NB + 1];
  __shared__ unsigned cand[3][CCAP];
  __shared__ int candn[3];
  __shared__ float redm[16], reds[16], redmin[16], redmax[16];
  __shared__ unsigned wsum[16];
  __shared__ int abin[3], acnt[3];
  __shared__ unsigned akey[3];
  __shared__ unsigned long long accg;
  __shared__ float gs0, gsm, s_logE, s_vmin, s_vmax;
  __shared__ int s_cnt;

  if (tid == 0) { s_cnt = 0; gs0 = 0.f; gsm = 0.f; accg = 0ull; }
  if (tid < 3) candn[tid] = 0;
  __syncthreads();

  // ---------- Pass A ----------
  const unsigned qm = qmask[tid];
  const unsigned pmask = lab ? qm : ~qm;
  const int base = tid << 5;
  float va[32];
#pragma unroll
  for (int u = 0; u < 8; ++u) {
    const float4 v = *reinterpret_cast<const float4*>(row + base + (u << 2));
    va[(u << 2) + 0] = v.x; va[(u << 2) + 1] = v.y;
    va[(u << 2) + 2] = v.z; va[(u << 2) + 3] = v.w;
  }
  float mneg = -3.0e38f, sneg = 0.f, vmin = 3.0e38f, vmax = -3.0e38f;
#pragma unroll
  for (int j = 0; j < 32; ++j) {
    if ((pmask >> j) & 1u) {
      vmin = fminf(vmin, va[j]);
      vmax = fmaxf(vmax, va[j]);
    } else {
      mneg = fmaxf(mneg, va[j] * TINV);
    }
  }
#pragma unroll
  for (int j = 0; j < 32; ++j) {
    if (!((pmask >> j) & 1u)) sneg += __expf(va[j] * TINV - mneg);
  }
#pragma unroll
  for (int o = 32; o; o >>= 1) {
    const float mo = __shfl_down(mneg, o), so = __shfl_down(sneg, o);
    const float M = fmaxf(mneg, mo);
    sneg = sneg * __expf(mneg - M) + so * __expf(mo - M);
    mneg = M;
    vmin = fminf(vmin, __shfl_down(vmin, o));
    vmax = fmaxf(vmax, __shfl_down(vmax, o));
  }
  if (lane == 0) { redm[wid] = mneg; reds[wid] = sneg; redmin[wid] = vmin; redmax[wid] = vmax; }

  const int np = __popc(pmask);
  unsigned incl = (unsigned)np;
#pragma unroll
  for (int o = 1; o < 64; o <<= 1) {
    const unsigned t = __shfl_up(incl, o);
    if (lane >= o) incl += t;
  }
  const unsigned excl = incl - (unsigned)np;
  const unsigned wtot = __shfl(incl, 63);
  unsigned wbase = 0u;
  if (lane == 63) wbase = (unsigned)atomicAdd(&s_cnt, (int)wtot);
  wbase = __shfl(wbase, 63);
  const int ofs = (int)(wbase + excl);
  if (ofs + np <= PCAP) {
#pragma unroll
    for (int j = 0; j < 32; ++j) {
      if ((pmask >> j) & 1u)
        poskeys[ofs + __popc(pmask & ((1u << j) - 1u))] = f2key(va[j]);
    }
  }
  __syncthreads();

  const int P = s_cnt;
  if (tid == 0) {
    float M = redm[0], S = 0.f;
    float mn = redmin[0], mx = redmax[0];
    for (int w = 1; w < 16; ++w) {
      M = fmaxf(M, redm[w]);
      mn = fminf(mn, redmin[w]);
      mx = fmaxf(mx, redmax[w]);
    }
    for (int w = 0; w < 16; ++w) S += reds[w] * __expf(redm[w] - M);
    s_logE = M + logf(S);
    s_vmin = mn;
    s_vmax = mx;
  }
  if (tid < ((4 - (P & 3)) & 3)) poskeys[P + tid] = 0u;
  for (int i = tid; i < NB + 1; i += 1024) hist[i] = 0u;
  __syncthreads();

  const float cE = s_logE;
  const float vmn = s_vmin;
  const float scale = (float)NB * (1.0f - 1e-6f) / fmaxf(s_vmax - vmn, 1e-30f);
  auto key2bin = [&](unsigned k) {
    int bn = (int)((key2f(k) - vmn) * scale);
    return bn < 0 ? 0 : (bn > NB - 1 ? NB - 1 : bn);
  };

  for (int i = tid; i < P; i += 1024) atomicAdd(&hist[key2bin(poskeys[i])], 1u);
  __syncthreads();

  const int t4 = tid << 2;
  const unsigned h0 = hist[t4], h1 = hist[t4 + 1], h2 = hist[t4 + 2], h3 = hist[t4 + 3];
  const unsigned part = h0 + h1 + h2 + h3;
  unsigned sinc = part;
#pragma unroll
  for (int o = 1; o < 64; o <<= 1) {
    const unsigned t = __shfl_up(sinc, o);
    if (lane >= o) sinc += t;
  }
  if (lane == 63) wsum[wid] = sinc;
  __syncthreads();
  unsigned woff = 0;
  for (int w = 0; w < wid; ++w) woff += wsum[w];
  const unsigned exb = woff + sinc - part;
  hist[t4] = exb; hist[t4 + 1] = exb + h0; hist[t4 + 2] = exb + h0 + h1;
  hist[t4 + 3] = exb + h0 + h1 + h2;
  if (tid == 1023) hist[NB] = exb + part;
  __syncthreads();

  const int rt0 = 25, rt1 = m - 25, rt2 = m;
  const unsigned idx0 = (unsigned)(P - rt0), idx1 = (unsigned)(P - rt1), idx2 = (unsigned)(P - rt2);
#pragma unroll
  for (int i = 0; i < 4; ++i) {
    const int bb = t4 + i;
    const unsigned pb = hist[bb], pb1 = hist[bb + 1];
    if (pb <= idx0 && idx0 < pb1) { abin[0] = bb; acnt[0] = P - (int)pb1; }
    if (pb <= idx1 && idx1 < pb1) { abin[1] = bb; acnt[1] = P - (int)pb1; }
    if (pb <= idx2 && idx2 < pb1) { abin[2] = bb; acnt[2] = P - (int)pb1; }
  }
  __syncthreads();

  const int tb0 = abin[0], tb1 = abin[1], tb2 = abin[2];
  for (int i = tid; i < P; i += 1024) {
    const unsigned k = poskeys[i];
    const int bn = key2bin(k);
    if (bn == tb0) { const int p = atomicAdd(&candn[0], 1); if (p < CCAP) cand[0][p] = k; }
    if (bn == tb1) { const int p = atomicAdd(&candn[1], 1); if (p < CCAP) cand[1][p] = k; }
    if (bn == tb2) { const int p = atomicAdd(&candn[2], 1); if (p < CCAP) cand[2][p] = k; }
  }
  __syncthreads();

  if (wid < 3) {
    const int j = wid;
    const int rts[3] = {rt0, rt1, rt2};
    const int cnt = candn[j] < CCAP ? candn[j] : CCAP;
    const int rr = rts[j] - acnt[j];
    for (int i = lane; i < cnt; i += 64) {
      const unsigned k = cand[j][i];
      int gt = 0, eq = 0;
      for (int q = 0; q < cnt; ++q) {
        const unsigned kq = cand[j][q];
        gt += (kq > k);
        eq += (kq == k);
      }
      if (gt < rr && rr <= gt + eq) akey[j] = k;
    }
  }
  __syncthreads();

  const unsigned a0 = akey[0], a1 = akey[1], a2 = akey[2];
  const int P4c = (P + 3) >> 2;
  const uint4* __restrict__ pk4 = reinterpret_cast<const uint4*>(poskeys);

  float s0 = 0.f, sm = 0.f;
  unsigned q0c = 0, q1c = 0, q2c = 0;
  for (int i = tid; i < P4c; i += 1024) {
    const uint4 kv = pk4[i];
    const unsigned ks[4] = {kv.x, kv.y, kv.z, kv.w};
#pragma unroll
    for (int j = 0; j < 4; ++j) {
      const unsigned k = ks[j];
      if (k > a2) {
        ++q2c;
        const bool top = (k > a0), mid = (k <= a1);
        if (k > a1) ++q1c;
        if (top) ++q0c;
        if (top || mid) {
          const float a = key2f(k) * TINV;
          const float d = cE - a;
          const float fv = fmaxf(d, 0.f) + log1pf(__expf(-fabsf(d)));
          if (top) s0 += fv;
          if (mid) sm += fv;
        }
      }
    }
  }
  unsigned long long pc = (unsigned long long)q0c |
                          ((unsigned long long)q1c << 20) |
                          ((unsigned long long)q2c << 40);
#pragma unroll
  for (int o = 32; o; o >>= 1) {
    s0 += __shfl_down(s0, o);
    sm += __shfl_down(sm, o);
    pc += shfl_down_u64(pc, o);
  }
  if (lane == 0) {
    atomicAdd(&gs0, s0);
    atomicAdd(&gsm, sm);
    atomicAdd(&accg, pc);
  }
  __syncthreads();
  if (tid == 0) {
    const unsigned long long t = accg;
    const float C0 = (float)(unsigned)(t & 0xFFFFFu);
    const float C1 = (float)(unsigned)((t >> 20) & 0xFFFFFu);
    const float C2 = (float)(unsigned)((t >> 40) & 0xFFFFFu);
    auto fval = [&](unsigned kk) {
      const float a = key2f(kk) * TINV;
      const float d = cE - a;
      return fmaxf(d, 0.f) + log1pf(__expf(-fabsf(d)));
    };
    const float f0 = fval(a0), f1 = fval(a1), f2 = fval(a2);
    const float top25 = gs0 + (25.0f - C0) * f0;
    const float mid = gsm + ((float)m - C2) * f2 - ((float)(m - 25) - C1) * f1;
    atomicAdd(out, 0.1f * (top25 + mid) * (1.0f / 6400.0f));
  }
}

extern "C" void kernel_launch(void* const* d_in, const int* in_sizes, int n_in,
                              void* d_out, int out_size, void* d_ws, size_t ws_size,
                              hipStream_t stream) {
  const float* pooled = (const float*)d_in[0];
  const int* labels = (const int*)d_in[1];
  const float* fq = (const float*)d_in[2];
  const int* lq = (const int*)d_in[3];
  const float* cls_dw = (const float*)d_in[4];
  const float* cls_db = (const float*)d_in[5];
  const float* cls_ow = (const float*)d_in[6];
  const float* cls_ob = (const float*)d_in[7];
  const float* con_dw = (const float*)d_in[8];
  const float* con_db = (const float*)d_in[9];
  const float* con_ow = (const float*)d_in[10];
  const float* con_ob = (const float*)d_in[11];
  float* out = (float*)d_out;

  float* ws = (float*)d_ws;
  float* H1 = ws;                                        // 128*768 f32
  float* H2 = ws + 98304;                                // 128*768 f32
  float* Y = ws + 2 * 98304;                             // 128*768 f32
  unsigned short* qh = (unsigned short*)(ws + 3 * 98304); // 128*768 bf16
  float* C = ws + 4 * 98304;                             // 128*32768 f32
  int* mptr = (int*)(ws + 4 * 98304 + (size_t)BB * KQ);
  unsigned* qmask = (unsigned*)(mptr + 1);               // 1024 words

  counts_kernel<<<1, 1024, 0, stream>>>(labels, lq, mptr, qmask, out);
  dense_pair<<<dim3(24, 4, 2), 256, 0, stream>>>(pooled, cls_dw, cls_db, H1,
                                                 con_dw, con_db, H2);
  gemm_bias<<<dim3(24, 4), 256, 0, stream>>>(H2, con_ow, con_ob, Y);
  l2norm_split<<<128, 256, 0, stream>>>(Y, qh);
  cls_loss_kernel<<<128, 256, 0, stream>>>(H1, cls_ow, cls_ob, labels, out);
  cos_gemm_mfma<<<256, 512, 0, stream>>>(qh, fq, C);
  select_kernel<<<128, 1024, 0, stream>>>(C, labels, qmask, mptr, out);
}

// Round 8
// 111.316 us; speedup vs baseline: 1.3272x; 1.3272x over previous
//
#include <hip/hip_runtime.h>
#include <math.h>

#define BB 128
#define HH 768
#define KQ 32768
#define PCAP 18432  // max positives per row staged in LDS
#define NB 4096     // histogram bins
#define CCAP 512    // candidate cap per target bin

constexpr float TINV = 1.0f / 0.07f;

typedef __attribute__((ext_vector_type(8))) short short8;
typedef __attribute__((ext_vector_type(4))) float f32x4;
typedef __attribute__((address_space(3))) void lds_void;
typedef const __attribute__((address_space(1))) void gbl_void;

__device__ __forceinline__ unsigned short f2bf(float f) {
  unsigned u = __float_as_uint(f);
  unsigned r = u + 0x7FFFu + ((u >> 16) & 1u);  // RNE
  return (unsigned short)(r >> 16);
}
__device__ __forceinline__ unsigned f2key(float f) {
  unsigned u = __float_as_uint(f);
  return u ^ (unsigned)(((int)u >> 31) | 0x80000000);
}
__device__ __forceinline__ float key2f(unsigned k) {
  unsigned u = (k & 0x80000000u) ? (k & 0x7FFFFFFFu) : ~k;
  return __uint_as_float(u);
}
__device__ __forceinline__ unsigned long long shfl_down_u64(unsigned long long v, int o) {
  unsigned lo = (unsigned)v, hi = (unsigned)(v >> 32);
  lo = __shfl_down(lo, o);
  hi = __shfl_down(hi, o);
  return ((unsigned long long)hi << 32) | lo;
}
__device__ __forceinline__ void gl16(const unsigned short* g, unsigned short* l) {
  __builtin_amdgcn_global_load_lds((gbl_void*)g, (lds_void*)l, 16, 0, 0);
}

// C = tanh(A @ W{0,1} + b{0,1}); z picks head. BM=BN=32, BK=32, 256 thr.
__global__ __launch_bounds__(256) void dense_pair(
    const float* __restrict__ A, const float* __restrict__ W0,
    const float* __restrict__ b0, float* __restrict__ C0,
    const float* __restrict__ W1, const float* __restrict__ b1,
    float* __restrict__ C1) {
  const float* W = blockIdx.z ? W1 : W0;
  const float* bias = blockIdx.z ? b1 : b0;
  float* Cout = blockIdx.z ? C1 : C0;
  __shared__ float As[32][33];
  __shared__ float Ws[32][36];
  const int n0 = blockIdx.x * 32;
  const int m0 = blockIdx.y * 32;
  const int tid = threadIdx.x;
  const int tn = tid & 15, tm = tid >> 4;
  const int r = tid >> 3, c = (tid & 7) << 2;
  float acc[2][2] = {};
  for (int k0 = 0; k0 < HH; k0 += 32) {
    const float4 a4 = *reinterpret_cast<const float4*>(A + (size_t)(m0 + r) * HH + k0 + c);
    As[c + 0][r] = a4.x; As[c + 1][r] = a4.y; As[c + 2][r] = a4.z; As[c + 3][r] = a4.w;
    const float4 w4 = *reinterpret_cast<const float4*>(W + (size_t)(k0 + r) * HH + n0 + c);
    *reinterpret_cast<float4*>(&Ws[r][c]) = w4;
    __syncthreads();
#pragma unroll
    for (int kk = 0; kk < 32; ++kk) {
      const float a0 = As[kk][tm * 2], a1 = As[kk][tm * 2 + 1];
      const float w0 = Ws[kk][tn * 2], w1 = Ws[kk][tn * 2 + 1];
      acc[0][0] = fmaf(a0, w0, acc[0][0]); acc[0][1] = fmaf(a0, w1, acc[0][1]);
      acc[1][0] = fmaf(a1, w0, acc[1][0]); acc[1][1] = fmaf(a1, w1, acc[1][1]);
    }
    __syncthreads();
  }
  const float b0v = bias[n0 + tn * 2], b1v = bias[n0 + tn * 2 + 1];
#pragma unroll
  for (int i = 0; i < 2; ++i) {
    float* dst = Cout + (size_t)(m0 + tm * 2 + i) * HH + n0 + tn * 2;
    dst[0] = tanhf(acc[i][0] + b0v);
    dst[1] = tanhf(acc[i][1] + b1v);
  }
}

// C = A @ W + b (no act). BM=BN=32, BK=32.
__global__ __launch_bounds__(256) void gemm_bias(
    const float* __restrict__ A, const float* __restrict__ W,
    const float* __restrict__ bias, float* __restrict__ Cout) {
  __shared__ float As[32][33];
  __shared__ float Ws[32][36];
  const int n0 = blockIdx.x * 32;
  const int m0 = blockIdx.y * 32;
  const int tid = threadIdx.x;
  const int tn = tid & 15, tm = tid >> 4;
  const int r = tid >> 3, c = (tid & 7) << 2;
  float acc[2][2] = {};
  for (int k0 = 0; k0 < HH; k0 += 32) {
    const float4 a4 = *reinterpret_cast<const float4*>(A + (size_t)(m0 + r) * HH + k0 + c);
    As[c + 0][r] = a4.x; As[c + 1][r] = a4.y; As[c + 2][r] = a4.z; As[c + 3][r] = a4.w;
    const float4 w4 = *reinterpret_cast<const float4*>(W + (size_t)(k0 + r) * HH + n0 + c);
    *reinterpret_cast<float4*>(&Ws[r][c]) = w4;
    __syncthreads();
#pragma unroll
    for (int kk = 0; kk < 32; ++kk) {
      const float a0 = As[kk][tm * 2], a1 = As[kk][tm * 2 + 1];
      const float w0 = Ws[kk][tn * 2], w1 = Ws[kk][tn * 2 + 1];
      acc[0][0] = fmaf(a0, w0, acc[0][0]); acc[0][1] = fmaf(a0, w1, acc[0][1]);
      acc[1][0] = fmaf(a1, w0, acc[1][0]); acc[1][1] = fmaf(a1, w1, acc[1][1]);
    }
    __syncthreads();
  }
  const float b0v = bias[n0 + tn * 2], b1v = bias[n0 + tn * 2 + 1];
#pragma unroll
  for (int i = 0; i < 2; ++i) {
    float* dst = Cout + (size_t)(m0 + tm * 2 + i) * HH + n0 + tn * 2;
    dst[0] = acc[i][0] + b0v;
    dst[1] = acc[i][1] + b1v;
  }
}

// cos GEMM v8: BM=128 x BN=64, 256 thr (4 waves), grid=512, 2 blocks/CU.
// A (qh) double-buffered in LDS, K-chunks of 128 (6 chunks, 6 barriers),
// staged via global_load_lds with XOR-swizzled pre-permuted source.
// B (fq) per-lane direct global->reg, 4-deep static rotating prefetch.
__global__ __launch_bounds__(256, 2) void cos_gemm_mfma(
    const unsigned short* __restrict__ qh, const float* __restrict__ FQ,
    float* __restrict__ C) {
  __shared__ unsigned short Abuf[2][128 * 128];  // 2 x 32 KB
  const int tid = threadIdx.x;
  const int lane = tid & 63, wid = tid >> 6;  // 4 waves
  const int bid = blockIdx.x;
  const int swz = (bid & 7) * 64 + (bid >> 3);  // bijective XCD swizzle (512%8==0)
  const int q0 = swz * 64;
  const int a_r = lane & 15, a_kq = lane >> 4;

  // A staging: 8 issues/thread-wave; issue j covers rows slab*4..slab*4+3
  // (slab = wid*8+j); lane l -> row slab*4 + (l>>4), slot kbs = l&15 holds
  // source kb = kbs ^ (row&15) (conflict-free swizzle; both-sides rule).
  int asrc[8];
#pragma unroll
  for (int j = 0; j < 8; ++j) {
    const int rr = (wid * 8 + j) * 4 + (lane >> 4);
    const int kb = (lane & 15) ^ (rr & 15);
    asrc[j] = rr * HH + kb * 8;  // halfword offset; + c*128 per chunk
  }

  // B: fq row = q0 + wid*16 + a_r (wave owns 16 cols), k = s*32 + a_kq*8.
  const float* __restrict__ bptr = FQ + (size_t)(q0 + wid * 16 + a_r) * HH + a_kq * 8;

  // compute-side A read: row = m*16 + a_r; in-chunk slot = (st*4+a_kq) ^ a_r.
  int aslot[4];
#pragma unroll
  for (int st = 0; st < 4; ++st) aslot[st] = (((st * 4 + a_kq) ^ a_r) << 3);

  f32x4 acc[8];
#pragma unroll
  for (int m = 0; m < 8; ++m) acc[m] = (f32x4){0.f, 0.f, 0.f, 0.f};

  // prologue: stage chunk 0; preload B s=0..3
#pragma unroll
  for (int j = 0; j < 8; ++j)
    gl16(qh + asrc[j], &Abuf[0][(wid * 8 + j) * 512]);
  float4 bv[4][2];
#pragma unroll
  for (int p = 0; p < 4; ++p) {
    bv[p][0] = *reinterpret_cast<const float4*>(bptr + p * 32);
    bv[p][1] = *reinterpret_cast<const float4*>(bptr + p * 32 + 4);
  }
  __syncthreads();

#pragma unroll
  for (int c = 0; c < 6; ++c) {
    if (c < 5) {
#pragma unroll
      for (int j = 0; j < 8; ++j)
        gl16(qh + (c + 1) * 128 + asrc[j], &Abuf[(c + 1) & 1][(wid * 8 + j) * 512]);
    }
    const unsigned short* __restrict__ Ab = Abuf[c & 1];
#pragma unroll
    for (int st = 0; st < 4; ++st) {
      const int s = c * 4 + st;
      const float4 v0 = bv[s & 3][0], v1 = bv[s & 3][1];
      if (s < 20) {
        bv[s & 3][0] = *reinterpret_cast<const float4*>(bptr + (s + 4) * 32);
        bv[s & 3][1] = *reinterpret_cast<const float4*>(bptr + (s + 4) * 32 + 4);
      }
      short8 bb;
      bb[0] = (short)f2bf(v0.x); bb[1] = (short)f2bf(v0.y);
      bb[2] = (short)f2bf(v0.z); bb[3] = (short)f2bf(v0.w);
      bb[4] = (short)f2bf(v1.x); bb[5] = (short)f2bf(v1.y);
      bb[6] = (short)f2bf(v1.z); bb[7] = (short)f2bf(v1.w);
      const int sl = aslot[st];
#pragma unroll
      for (int m = 0; m < 8; ++m) {
        const short8 aa =
            *reinterpret_cast<const short8*>(&Ab[(m * 16 + a_r) * 128 + sl]);
        acc[m] = __builtin_amdgcn_mfma_f32_16x16x32_bf16(aa, bb, acc[m], 0, 0, 0);
      }
    }
    if (c < 5) __syncthreads();
  }

  // C[row][col]: row = m*16 + a_kq*4 + r (batch), col = q0 + wid*16 + a_r
  const int ccol = q0 + wid * 16 + a_r;
#pragma unroll
  for (int m = 0; m < 8; ++m)
#pragma unroll
    for (int r = 0; r < 4; ++r)
      C[(size_t)(m * 16 + a_kq * 4 + r) * KQ + ccol] = acc[m][r];
}

// L2-normalize rows of Y and emit bf16.
__global__ __launch_bounds__(256) void l2norm_split(const float* __restrict__ Y,
                                                    unsigned short* __restrict__ qh) {
  const int b = blockIdx.x, tid = threadIdx.x;
  __shared__ float sh[4];
  __shared__ float snorm;
  float ss = 0.f;
  for (int h = tid; h < HH; h += 256) {
    const float v = Y[(size_t)b * HH + h];
    ss = fmaf(v, v, ss);
  }
  for (int o = 32; o; o >>= 1) ss += __shfl_down(ss, o);
  const int lane = tid & 63, wid = tid >> 6;
  if (lane == 0) sh[wid] = ss;
  __syncthreads();
  if (tid == 0) snorm = 1.0f / sqrtf(sh[0] + sh[1] + sh[2] + sh[3]);
  __syncthreads();
  const float rs = snorm;
  for (int h = tid; h < HH; h += 256)
    qh[(size_t)b * HH + h] = f2bf(Y[(size_t)b * HH + h] * rs);
}

__global__ __launch_bounds__(256) void cls_loss_kernel(
    const float* __restrict__ H1, const float* __restrict__ W2,
    const float* __restrict__ b2, const int* __restrict__ labels,
    float* __restrict__ out) {
  const int b = blockIdx.x, tid = threadIdx.x;
  __shared__ float sh0[4], sh1[4];
  float p0 = 0.f, p1 = 0.f;
  for (int h = tid; h < HH; h += 256) {
    const float v = H1[(size_t)b * HH + h];
    p0 = fmaf(v, W2[h * 2 + 0], p0);
    p1 = fmaf(v, W2[h * 2 + 1], p1);
  }
  for (int o = 32; o; o >>= 1) {
    p0 += __shfl_down(p0, o);
    p1 += __shfl_down(p1, o);
  }
  const int lane = tid & 63, wid = tid >> 6;
  if (lane == 0) { sh0[wid] = p0; sh1[wid] = p1; }
  __syncthreads();
  if (tid == 0) {
    const float l0 = sh0[0] + sh0[1] + sh0[2] + sh0[3] + b2[0];
    const float l1 = sh1[0] + sh1[1] + sh1[2] + sh1[3] + b2[1];
    const float mx = fmaxf(l0, l1), mn = fminf(l0, l1);
    const float lse = mx + log1pf(__expf(mn - mx));
    const float ce = lse - (labels[b] ? l1 : l0);
    atomicAdd(out, 0.9f * ce * (1.0f / 128.0f));
  }
}

// Also zeroes out[0] and builds qmask (bit=1 iff label_queue[k]==1).
__global__ __launch_bounds__(1024) void counts_kernel(const int* __restrict__ labels,
                                                      const int* __restrict__ lq,
                                                      int* __restrict__ m_out,
                                                      unsigned* __restrict__ qmask,
                                                      float* __restrict__ out) {
  const int tid = threadIdx.x;
  __shared__ int sh[16];
  __shared__ int has[2];
  unsigned mask = 0u;
  const int base = tid << 5;
#pragma unroll
  for (int j = 0; j < 32; ++j) mask |= (unsigned)(lq[base + j] != 0) << j;
  qmask[tid] = mask;
  int c = __popc(mask);
  for (int o = 32; o; o >>= 1) c += __shfl_down(c, o);
  const int lane = tid & 63, wid = tid >> 6;
  if (tid < 2) has[tid] = 0;
  __syncthreads();
  if (lane == 0) sh[wid] = c;
  if (tid < BB) has[labels[tid]] = 1;
  __syncthreads();
  if (tid == 0) {
    int n1 = 0;
    for (int w = 0; w < 16; ++w) n1 += sh[w];
    const int n0 = KQ - n1;
    int mm = 0x7fffffff;
    if (has[0] && n0 < mm) mm = n0;
    if (has[1] && n1 < mm) mm = n1;
    *m_out = mm;
    out[0] = 0.0f;
  }
}

// Pass A (row read + neg-lse + pos key compaction + pos min/max), then
// histogram radix-select for ranks {25, m-25, m}, then one gather pass.
__global__ __launch_bounds__(1024) void select_kernel(
    const float* __restrict__ Cm, const int* __restrict__ labels,
    const unsigned* __restrict__ qmask, const int* __restrict__ m_ptr,
    float* __restrict__ out) {
  const int b = blockIdx.x;
  const int tid = threadIdx.x;
  const int lane = tid & 63, wid = tid >> 6;
  const float* __restrict__ row = Cm + (size_t)b * KQ;
  const int lab = labels[b];
  const int m = *m_ptr;

  __shared__ __align__(16) unsigned poskeys[PCAP];
  __shared__ unsigned hist[NB + 1];
  __shared__ unsigned cand[3][CCAP];
  __shared__ int candn[3];
  __shared__ float redm[16], reds[16], redmin[16], redmax[16];
  __shared__ unsigned wsum[16];
  __shared__ int abin[3], acnt[3];
  __shared__ unsigned akey[3];
  __shared__ unsigned long long accg;
  __shared__ float gs0, gsm, s_logE, s_vmin, s_vmax;
  __shared__ int s_cnt;

  if (tid == 0) { s_cnt = 0; gs0 = 0.f; gsm = 0.f; accg = 0ull; }
  if (tid < 3) candn[tid] = 0;
  __syncthreads();

  // ---------- Pass A ----------
  const unsigned qm = qmask[tid];
  const unsigned pmask = lab ? qm : ~qm;
  const int base = tid << 5;
  float va[32];
#pragma unroll
  for (int u = 0; u < 8; ++u) {
    const float4 v = *reinterpret_cast<const float4*>(row + base + (u << 2));
    va[(u << 2) + 0] = v.x; va[(u << 2) + 1] = v.y;
    va[(u << 2) + 2] = v.z; va[(u << 2) + 3] = v.w;
  }
  float mneg = -3.0e38f, sneg = 0.f, vmin = 3.0e38f, vmax = -3.0e38f;
#pragma unroll
  for (int j = 0; j < 32; ++j) {
    if ((pmask >> j) & 1u) {
      vmin = fminf(vmin, va[j]);
      vmax = fmaxf(vmax, va[j]);
    } else {
      mneg = fmaxf(mneg, va[j] * TINV);
    }
  }
#pragma unroll
  for (int j = 0; j < 32; ++j) {
    if (!((pmask >> j) & 1u)) sneg += __expf(va[j] * TINV - mneg);
  }
#pragma unroll
  for (int o = 32; o; o >>= 1) {
    const float mo = __shfl_down(mneg, o), so = __shfl_down(sneg, o);
    const float M = fmaxf(mneg, mo);
    sneg = sneg * __expf(mneg - M) + so * __expf(mo - M);
    mneg = M;
    vmin = fminf(vmin, __shfl_down(vmin, o));
    vmax = fmaxf(vmax, __shfl_down(vmax, o));
  }
  if (lane == 0) { redm[wid] = mneg; reds[wid] = sneg; redmin[wid] = vmin; redmax[wid] = vmax; }

  const int np = __popc(pmask);
  unsigned incl = (unsigned)np;
#pragma unroll
  for (int o = 1; o < 64; o <<= 1) {
    const unsigned t = __shfl_up(incl, o);
    if (lane >= o) incl += t;
  }
  const unsigned excl = incl - (unsigned)np;
  const unsigned wtot = __shfl(incl, 63);
  unsigned wbase = 0u;
  if (lane == 63) wbase = (unsigned)atomicAdd(&s_cnt, (int)wtot);
  wbase = __shfl(wbase, 63);
  const int ofs = (int)(wbase + excl);
  if (ofs + np <= PCAP) {
#pragma unroll
    for (int j = 0; j < 32; ++j) {
      if ((pmask >> j) & 1u)
        poskeys[ofs + __popc(pmask & ((1u << j) - 1u))] = f2key(va[j]);
    }
  }
  __syncthreads();

  const int P = s_cnt;
  if (tid == 0) {
    float M = redm[0], S = 0.f;
    float mn = redmin[0], mx = redmax[0];
    for (int w = 1; w < 16; ++w) {
      M = fmaxf(M, redm[w]);
      mn = fminf(mn, redmin[w]);
      mx = fmaxf(mx, redmax[w]);
    }
    for (int w = 0; w < 16; ++w) S += reds[w] * __expf(redm[w] - M);
    s_logE = M + logf(S);
    s_vmin = mn;
    s_vmax = mx;
  }
  if (tid < ((4 - (P & 3)) & 3)) poskeys[P + tid] = 0u;
  for (int i = tid; i < NB + 1; i += 1024) hist[i] = 0u;
  __syncthreads();

  const float cE = s_logE;
  const float vmn = s_vmin;
  const float scale = (float)NB * (1.0f - 1e-6f) / fmaxf(s_vmax - vmn, 1e-30f);
  auto key2bin = [&](unsigned k) {
    int bn = (int)((key2f(k) - vmn) * scale);
    return bn < 0 ? 0 : (bn > NB - 1 ? NB - 1 : bn);
  };

  for (int i = tid; i < P; i += 1024) atomicAdd(&hist[key2bin(poskeys[i])], 1u);
  __syncthreads();

  const int t4 = tid << 2;
  const unsigned h0 = hist[t4], h1 = hist[t4 + 1], h2 = hist[t4 + 2], h3 = hist[t4 + 3];
  const unsigned part = h0 + h1 + h2 + h3;
  unsigned sinc = part;
#pragma unroll
  for (int o = 1; o < 64; o <<= 1) {
    const unsigned t = __shfl_up(sinc, o);
    if (lane >= o) sinc += t;
  }
  if (lane == 63) wsum[wid] = sinc;
  __syncthreads();
  unsigned woff = 0;
  for (int w = 0; w < wid; ++w) woff += wsum[w];
  const unsigned exb = woff + sinc - part;
  hist[t4] = exb; hist[t4 + 1] = exb + h0; hist[t4 + 2] = exb + h0 + h1;
  hist[t4 + 3] = exb + h0 + h1 + h2;
  if (tid == 1023) hist[NB] = exb + part;
  __syncthreads();

  const int rt0 = 25, rt1 = m - 25, rt2 = m;
  const unsigned idx0 = (unsigned)(P - rt0), idx1 = (unsigned)(P - rt1), idx2 = (unsigned)(P - rt2);
#pragma unroll
  for (int i = 0; i < 4; ++i) {
    const int bb = t4 + i;
    const unsigned pb = hist[bb], pb1 = hist[bb + 1];
    if (pb <= idx0 && idx0 < pb1) { abin[0] = bb; acnt[0] = P - (int)pb1; }
    if (pb <= idx1 && idx1 < pb1) { abin[1] = bb; acnt[1] = P - (int)pb1; }
    if (pb <= idx2 && idx2 < pb1) { abin[2] = bb; acnt[2] = P - (int)pb1; }
  }
  __syncthreads();

  const int tb0 = abin[0], tb1 = abin[1], tb2 = abin[2];
  for (int i = tid; i < P; i += 1024) {
    const unsigned k = poskeys[i];
    const int bn = key2bin(k);
    if (bn == tb0) { const int p = atomicAdd(&candn[0], 1); if (p < CCAP) cand[0][p] = k; }
    if (bn == tb1) { const int p = atomicAdd(&candn[1], 1); if (p < CCAP) cand[1][p] = k; }
    if (bn == tb2) { const int p = atomicAdd(&candn[2], 1); if (p < CCAP) cand[2][p] = k; }
  }
  __syncthreads();

  if (wid < 3) {
    const int j = wid;
    const int rts[3] = {rt0, rt1, rt2};
    const int cnt = candn[j] < CCAP ? candn[j] : CCAP;
    const int rr = rts[j] - acnt[j];
    for (int i = lane; i < cnt; i += 64) {
      const unsigned k = cand[j][i];
      int gt = 0, eq = 0;
      for (int q = 0; q < cnt; ++q) {
        const unsigned kq = cand[j][q];
        gt += (kq > k);
        eq += (kq == k);
      }
      if (gt < rr && rr <= gt + eq) akey[j] = k;
    }
  }
  __syncthreads();

  const unsigned a0 = akey[0], a1 = akey[1], a2 = akey[2];
  const int P4c = (P + 3) >> 2;
  const uint4* __restrict__ pk4 = reinterpret_cast<const uint4*>(poskeys);

  float s0 = 0.f, sm = 0.f;
  unsigned q0c = 0, q1c = 0, q2c = 0;
  for (int i = tid; i < P4c; i += 1024) {
    const uint4 kv = pk4[i];
    const unsigned ks[4] = {kv.x, kv.y, kv.z, kv.w};
#pragma unroll
    for (int j = 0; j < 4; ++j) {
      const unsigned k = ks[j];
      if (k > a2) {
        ++q2c;
        const bool top = (k > a0), mid = (k <= a1);
        if (k > a1) ++q1c;
        if (top) ++q0c;
        if (top || mid) {
          const float a = key2f(k) * TINV;
          const float d = cE - a;
          const float fv = fmaxf(d, 0.f) + log1pf(__expf(-fabsf(d)));
          if (top) s0 += fv;
          if (mid) sm += fv;
        }
      }
    }
  }
  unsigned long long pc = (unsigned long long)q0c |
                          ((unsigned long long)q1c << 20) |
                          ((unsigned long long)q2c << 40);
#pragma unroll
  for (int o = 32; o; o >>= 1) {
    s0 += __shfl_down(s0, o);
    sm += __shfl_down(sm, o);
    pc += shfl_down_u64(pc, o);
  }
  if (lane == 0) {
    atomicAdd(&gs0, s0);
    atomicAdd(&gsm, sm);
    atomicAdd(&accg, pc);
  }
  __syncthreads();
  if (tid == 0) {
    const unsigned long long t = accg;
    const float C0 = (float)(unsigned)(t & 0xFFFFFu);
    const float C1 = (float)(unsigned)((t >> 20) & 0xFFFFFu);
    const float C2 = (float)(unsigned)((t >> 40) & 0xFFFFFu);
    auto fval = [&](unsigned kk) {
      const float a = key2f(kk) * TINV;
      const float d = cE - a;
      return fmaxf(d, 0.f) + log1pf(__expf(-fabsf(d)));
    };
    const float f0 = fval(a0), f1 = fval(a1), f2 = fval(a2);
    const float top25 = gs0 + (25.0f - C0) * f0;
    const float mid = gsm + ((float)m - C2) * f2 - ((float)(m - 25) - C1) * f1;
    atomicAdd(out, 0.1f * (top25 + mid) * (1.0f / 6400.0f));
  }
}

extern "C" void kernel_launch(void* const* d_in, const int* in_sizes, int n_in,
                              void* d_out, int out_size, void* d_ws, size_t ws_size,
                              hipStream_t stream) {
  const float* pooled = (const float*)d_in[0];
  const int* labels = (const int*)d_in[1];
  const float* fq = (const float*)d_in[2];
  const int* lq = (const int*)d_in[3];
  const float* cls_dw = (const float*)d_in[4];
  const float* cls_db = (const float*)d_in[5];
  const float* cls_ow = (const float*)d_in[6];
  const float* cls_ob = (const float*)d_in[7];
  const float* con_dw = (const float*)d_in[8];
  const float* con_db = (const float*)d_in[9];
  const float* con_ow = (const float*)d_in[10];
  const float* con_ob = (const float*)d_in[11];
  float* out = (float*)d_out;

  float* ws = (float*)d_ws;
  float* H1 = ws;                                        // 128*768 f32
  float* H2 = ws + 98304;                                // 128*768 f32
  float* Y = ws + 2 * 98304;                             // 128*768 f32
  unsigned short* qh = (unsigned short*)(ws + 3 * 98304); // 128*768 bf16
  float* C = ws + 4 * 98304;                             // 128*32768 f32
  int* mptr = (int*)(ws + 4 * 98304 + (size_t)BB * KQ);
  unsigned* qmask = (unsigned*)(mptr + 1);               // 1024 words

  counts_kernel<<<1, 1024, 0, stream>>>(labels, lq, mptr, qmask, out);
  dense_pair<<<dim3(24, 4, 2), 256, 0, stream>>>(pooled, cls_dw, cls_db, H1,
                                                 con_dw, con_db, H2);
  gemm_bias<<<dim3(24, 4), 256, 0, stream>>>(H2, con_ow, con_ob, Y);
  l2norm_split<<<128, 256, 0, stream>>>(Y, qh);
  cls_loss_kernel<<<128, 256, 0, stream>>>(H1, cls_ow, cls_ob, labels, out);
  cos_gemm_mfma<<<512, 256, 0, stream>>>(qh, fq, C);
  select_kernel<<<128, 1024, 0, stream>>>(C, labels, qmask, mptr, out);
}

// Round 9
// 106.575 us; speedup vs baseline: 1.3862x; 1.0445x over previous
//
#include <hip/hip_runtime.h>
#include <math.h>

#define BB 128
#define HH 768
#define KQ 32768
#define PCAP 18432  // max positives per row staged in LDS
#define NB 4096     // histogram bins
#define CCAP 512    // candidate cap per target bin

constexpr float TINV = 1.0f / 0.07f;

typedef __attribute__((ext_vector_type(8))) short short8;
typedef __attribute__((ext_vector_type(4))) float f32x4;
typedef __attribute__((address_space(3))) void lds_void;
typedef const __attribute__((address_space(1))) void gbl_void;

__device__ __forceinline__ unsigned short f2bf(float f) {
  unsigned u = __float_as_uint(f);
  unsigned r = u + 0x7FFFu + ((u >> 16) & 1u);  // RNE
  return (unsigned short)(r >> 16);
}
__device__ __forceinline__ unsigned f2key(float f) {
  unsigned u = __float_as_uint(f);
  return u ^ (unsigned)(((int)u >> 31) | 0x80000000);
}
__device__ __forceinline__ float key2f(unsigned k) {
  unsigned u = (k & 0x80000000u) ? (k & 0x7FFFFFFFu) : ~k;
  return __uint_as_float(u);
}
__device__ __forceinline__ unsigned long long shfl_down_u64(unsigned long long v, int o) {
  unsigned lo = (unsigned)v, hi = (unsigned)(v >> 32);
  lo = __shfl_down(lo, o);
  hi = __shfl_down(hi, o);
  return ((unsigned long long)hi << 32) | lo;
}
__device__ __forceinline__ void gl16(const unsigned short* g, unsigned short* l) {
  __builtin_amdgcn_global_load_lds((gbl_void*)g, (lds_void*)l, 16, 0, 0);
}

// C = tanh(A @ W{0,1} + b{0,1}); z picks head. Also zeroes out[0] (block 0).
__global__ __launch_bounds__(256) void dense_pair(
    const float* __restrict__ A, const float* __restrict__ W0,
    const float* __restrict__ b0, float* __restrict__ C0,
    const float* __restrict__ W1, const float* __restrict__ b1,
    float* __restrict__ C1, float* __restrict__ out) {
  if (blockIdx.x == 0 && blockIdx.y == 0 && blockIdx.z == 0 && threadIdx.x == 0)
    out[0] = 0.0f;
  const float* W = blockIdx.z ? W1 : W0;
  const float* bias = blockIdx.z ? b1 : b0;
  float* Cout = blockIdx.z ? C1 : C0;
  __shared__ float As[32][33];
  __shared__ float Ws[32][36];
  const int n0 = blockIdx.x * 32;
  const int m0 = blockIdx.y * 32;
  const int tid = threadIdx.x;
  const int tn = tid & 15, tm = tid >> 4;
  const int r = tid >> 3, c = (tid & 7) << 2;
  float acc[2][2] = {};
  for (int k0 = 0; k0 < HH; k0 += 32) {
    const float4 a4 = *reinterpret_cast<const float4*>(A + (size_t)(m0 + r) * HH + k0 + c);
    As[c + 0][r] = a4.x; As[c + 1][r] = a4.y; As[c + 2][r] = a4.z; As[c + 3][r] = a4.w;
    const float4 w4 = *reinterpret_cast<const float4*>(W + (size_t)(k0 + r) * HH + n0 + c);
    *reinterpret_cast<float4*>(&Ws[r][c]) = w4;
    __syncthreads();
#pragma unroll
    for (int kk = 0; kk < 32; ++kk) {
      const float a0 = As[kk][tm * 2], a1 = As[kk][tm * 2 + 1];
      const float w0 = Ws[kk][tn * 2], w1 = Ws[kk][tn * 2 + 1];
      acc[0][0] = fmaf(a0, w0, acc[0][0]); acc[0][1] = fmaf(a0, w1, acc[0][1]);
      acc[1][0] = fmaf(a1, w0, acc[1][0]); acc[1][1] = fmaf(a1, w1, acc[1][1]);
    }
    __syncthreads();
  }
  const float b0v = bias[n0 + tn * 2], b1v = bias[n0 + tn * 2 + 1];
#pragma unroll
  for (int i = 0; i < 2; ++i) {
    float* dst = Cout + (size_t)(m0 + tm * 2 + i) * HH + n0 + tn * 2;
    dst[0] = tanhf(acc[i][0] + b0v);
    dst[1] = tanhf(acc[i][1] + b1v);
  }
}

// C = A @ W + b (no act). BM=BN=32, BK=32.
__global__ __launch_bounds__(256) void gemm_bias(
    const float* __restrict__ A, const float* __restrict__ W,
    const float* __restrict__ bias, float* __restrict__ Cout) {
  __shared__ float As[32][33];
  __shared__ float Ws[32][36];
  const int n0 = blockIdx.x * 32;
  const int m0 = blockIdx.y * 32;
  const int tid = threadIdx.x;
  const int tn = tid & 15, tm = tid >> 4;
  const int r = tid >> 3, c = (tid & 7) << 2;
  float acc[2][2] = {};
  for (int k0 = 0; k0 < HH; k0 += 32) {
    const float4 a4 = *reinterpret_cast<const float4*>(A + (size_t)(m0 + r) * HH + k0 + c);
    As[c + 0][r] = a4.x; As[c + 1][r] = a4.y; As[c + 2][r] = a4.z; As[c + 3][r] = a4.w;
    const float4 w4 = *reinterpret_cast<const float4*>(W + (size_t)(k0 + r) * HH + n0 + c);
    *reinterpret_cast<float4*>(&Ws[r][c]) = w4;
    __syncthreads();
#pragma unroll
    for (int kk = 0; kk < 32; ++kk) {
      const float a0 = As[kk][tm * 2], a1 = As[kk][tm * 2 + 1];
      const float w0 = Ws[kk][tn * 2], w1 = Ws[kk][tn * 2 + 1];
      acc[0][0] = fmaf(a0, w0, acc[0][0]); acc[0][1] = fmaf(a0, w1, acc[0][1]);
      acc[1][0] = fmaf(a1, w0, acc[1][0]); acc[1][1] = fmaf(a1, w1, acc[1][1]);
    }
    __syncthreads();
  }
  const float b0v = bias[n0 + tn * 2], b1v = bias[n0 + tn * 2 + 1];
#pragma unroll
  for (int i = 0; i < 2; ++i) {
    float* dst = Cout + (size_t)(m0 + tm * 2 + i) * HH + n0 + tn * 2;
    dst[0] = acc[i][0] + b0v;
    dst[1] = acc[i][1] + b1v;
  }
}

// cos GEMM v9: BM=128 x BN=64, 256 thr (4 waves), grid=512, 2 blocks/CU.
// A (qh) double-buffered LDS, K-chunks of 128; counted-vmcnt raw barriers
// keep the 8-deep B register prefetch in flight across chunk boundaries.
__global__ __launch_bounds__(256, 2) void cos_gemm_mfma(
    const unsigned short* __restrict__ qh, const float* __restrict__ FQ,
    float* __restrict__ C) {
  __shared__ unsigned short Abuf[2][128 * 128];  // 2 x 32 KB
  const int tid = threadIdx.x;
  const int lane = tid & 63, wid = tid >> 6;  // 4 waves
  const int bid = blockIdx.x;
  const int swz = (bid & 7) * 64 + (bid >> 3);  // bijective XCD swizzle (512%8==0)
  const int q0 = swz * 64;
  const int a_r = lane & 15, a_kq = lane >> 4;

  // A staging (conflict-free swizzle, source-permuted; rule both-sides)
  int asrc[8], adst[8];
#pragma unroll
  for (int j = 0; j < 8; ++j) {
    const int rr = (wid * 8 + j) * 4 + (lane >> 4);
    const int kb = (lane & 15) ^ (rr & 15);
    asrc[j] = rr * HH + kb * 8;
    adst[j] = (wid * 8 + j) * 512;
  }
  // B: fq row = q0 + wid*16 + a_r; k = s*32 + a_kq*8
  const float* __restrict__ bptr = FQ + (size_t)(q0 + wid * 16 + a_r) * HH + a_kq * 8;
  // compute-side A slot within chunk
  int aslot[4];
#pragma unroll
  for (int st = 0; st < 4; ++st) aslot[st] = (((st * 4 + a_kq) ^ a_r) << 3);

  f32x4 acc[8];
#pragma unroll
  for (int m = 0; m < 8; ++m) acc[m] = (f32x4){0.f, 0.f, 0.f, 0.f};

  // prologue: stage chunk 0; preload B s=0..7 (8-deep)
#pragma unroll
  for (int j = 0; j < 8; ++j) gl16(qh + asrc[j], &Abuf[0][adst[j]]);
  float4 bv[8][2];
#pragma unroll
  for (int p = 0; p < 8; ++p) {
    bv[p][0] = *reinterpret_cast<const float4*>(bptr + p * 32);
    bv[p][1] = *reinterpret_cast<const float4*>(bptr + p * 32 + 4);
  }
  asm volatile("s_waitcnt vmcnt(16)" ::: "memory");  // 8 gl16 retired; B in flight
  __builtin_amdgcn_s_barrier();
  __builtin_amdgcn_sched_barrier(0);

#pragma unroll
  for (int c = 0; c < 6; ++c) {
    if (c < 5) {
#pragma unroll
      for (int j = 0; j < 8; ++j)
        gl16(qh + (c + 1) * 128 + asrc[j], &Abuf[(c + 1) & 1][adst[j]]);
    }
    const unsigned short* __restrict__ Ab = Abuf[c & 1];
#pragma unroll
    for (int st = 0; st < 4; ++st) {
      const int s = c * 4 + st;
      const float4 v0 = bv[s & 7][0], v1 = bv[s & 7][1];
      if (s + 8 < 24) {
        bv[s & 7][0] = *reinterpret_cast<const float4*>(bptr + (s + 8) * 32);
        bv[s & 7][1] = *reinterpret_cast<const float4*>(bptr + (s + 8) * 32 + 4);
      }
      short8 bb;
      bb[0] = (short)f2bf(v0.x); bb[1] = (short)f2bf(v0.y);
      bb[2] = (short)f2bf(v0.z); bb[3] = (short)f2bf(v0.w);
      bb[4] = (short)f2bf(v1.x); bb[5] = (short)f2bf(v1.y);
      bb[6] = (short)f2bf(v1.z); bb[7] = (short)f2bf(v1.w);
      const int sl = aslot[st];
#pragma unroll
      for (int m = 0; m < 8; ++m) {
        const short8 aa =
            *reinterpret_cast<const short8*>(&Ab[(m * 16 + a_r) * 128 + sl]);
        acc[m] = __builtin_amdgcn_mfma_f32_16x16x32_bf16(aa, bb, acc[m], 0, 0, 0);
      }
    }
    if (c < 5) {
      // chunks 0..3: exactly 8 B-loads issued after this chunk's gl16 batch
      // -> vmcnt(8) guarantees gl16s retired (in-order), B stays in flight.
      // chunk 4: steps 16-19 issue no B loads -> must drain to 0.
      if (c < 4) asm volatile("s_waitcnt vmcnt(8)" ::: "memory");
      else       asm volatile("s_waitcnt vmcnt(0)" ::: "memory");
      __builtin_amdgcn_s_barrier();
      __builtin_amdgcn_sched_barrier(0);
    }
  }

  const int ccol = q0 + wid * 16 + a_r;
#pragma unroll
  for (int m = 0; m < 8; ++m)
#pragma unroll
    for (int r = 0; r < 4; ++r)
      C[(size_t)(m * 16 + a_kq * 4 + r) * KQ + ccol] = acc[m][r];
}

// Fused: blocks 0..127 l2norm(Y)->qh bf16; blocks 128..255 cls CE loss.
__global__ __launch_bounds__(256) void aux_kernel(
    const float* __restrict__ Y, unsigned short* __restrict__ qh,
    const float* __restrict__ H1, const float* __restrict__ W2,
    const float* __restrict__ b2, const int* __restrict__ labels,
    float* __restrict__ out) {
  const int tid = threadIdx.x;
  const int lane = tid & 63, wid = tid >> 6;
  __shared__ float sh0[4], sh1[4];
  __shared__ float snorm;
  if (blockIdx.x < 128) {
    const int b = blockIdx.x;
    float ss = 0.f;
    for (int h = tid; h < HH; h += 256) {
      const float v = Y[(size_t)b * HH + h];
      ss = fmaf(v, v, ss);
    }
    for (int o = 32; o; o >>= 1) ss += __shfl_down(ss, o);
    if (lane == 0) sh0[wid] = ss;
    __syncthreads();
    if (tid == 0) snorm = 1.0f / sqrtf(sh0[0] + sh0[1] + sh0[2] + sh0[3]);
    __syncthreads();
    const float rs = snorm;
    for (int h = tid; h < HH; h += 256)
      qh[(size_t)b * HH + h] = f2bf(Y[(size_t)b * HH + h] * rs);
  } else {
    const int b = blockIdx.x - 128;
    float p0 = 0.f, p1 = 0.f;
    for (int h = tid; h < HH; h += 256) {
      const float v = H1[(size_t)b * HH + h];
      p0 = fmaf(v, W2[h * 2 + 0], p0);
      p1 = fmaf(v, W2[h * 2 + 1], p1);
    }
    for (int o = 32; o; o >>= 1) {
      p0 += __shfl_down(p0, o);
      p1 += __shfl_down(p1, o);
    }
    if (lane == 0) { sh0[wid] = p0; sh1[wid] = p1; }
    __syncthreads();
    if (tid == 0) {
      const float l0 = sh0[0] + sh0[1] + sh0[2] + sh0[3] + b2[0];
      const float l1 = sh1[0] + sh1[1] + sh1[2] + sh1[3] + b2[1];
      const float mx = fmaxf(l0, l1), mn = fminf(l0, l1);
      const float lse = mx + log1pf(__expf(mn - mx));
      const float ce = lse - (labels[b] ? l1 : l0);
      atomicAdd(out, 0.9f * ce * (1.0f / 128.0f));
    }
  }
}

// Self-contained select: builds qmask/m from lq+labels, then pass A (neg-lse +
// pos compaction), histogram radix-select for ranks {25,m-25,m}, gather.
__global__ __launch_bounds__(1024) void select_kernel(
    const float* __restrict__ Cm, const int* __restrict__ labels,
    const int* __restrict__ lq, float* __restrict__ out) {
  const int b = blockIdx.x;
  const int tid = threadIdx.x;
  const int lane = tid & 63, wid = tid >> 6;
  const float* __restrict__ row = Cm + (size_t)b * KQ;
  const int lab = labels[b];

  __shared__ __align__(16) unsigned poskeys[PCAP];
  __shared__ unsigned hist[NB + 1];
  __shared__ unsigned cand[3][CCAP];
  __shared__ int candn[3];
  __shared__ float redm[16], reds[16], redmin[16], redmax[16];
  __shared__ int redn[16];
  __shared__ unsigned wsum[16];
  __shared__ int abin[3], acnt[3];
  __shared__ unsigned akey[3];
  __shared__ unsigned long long accg;
  __shared__ float gs0, gsm, s_logE, s_vmin, s_vmax;
  __shared__ int s_cnt, s_m, has01;

  if (tid == 0) { s_cnt = 0; gs0 = 0.f; gsm = 0.f; accg = 0ull; has01 = 0; }
  if (tid < 3) candn[tid] = 0;
  __syncthreads();

  // ---------- Pass A ----------
  const int base = tid << 5;
  unsigned qm = 0u;
  {
    const int4* __restrict__ lq4 = reinterpret_cast<const int4*>(lq + base);
#pragma unroll
    for (int u = 0; u < 8; ++u) {
      const int4 q = lq4[u];
      qm |= (unsigned)(q.x != 0) << (u * 4 + 0);
      qm |= (unsigned)(q.y != 0) << (u * 4 + 1);
      qm |= (unsigned)(q.z != 0) << (u * 4 + 2);
      qm |= (unsigned)(q.w != 0) << (u * 4 + 3);
    }
  }
  if (tid < BB) atomicOr(&has01, 1 << labels[tid]);
  const unsigned pmask = lab ? qm : ~qm;
  float va[32];
#pragma unroll
  for (int u = 0; u < 8; ++u) {
    const float4 v = *reinterpret_cast<const float4*>(row + base + (u << 2));
    va[(u << 2) + 0] = v.x; va[(u << 2) + 1] = v.y;
    va[(u << 2) + 2] = v.z; va[(u << 2) + 3] = v.w;
  }
  float mneg = -3.0e38f, sneg = 0.f, vmin = 3.0e38f, vmax = -3.0e38f;
#pragma unroll
  for (int j = 0; j < 32; ++j) {
    if ((pmask >> j) & 1u) {
      vmin = fminf(vmin, va[j]);
      vmax = fmaxf(vmax, va[j]);
    } else {
      mneg = fmaxf(mneg, va[j] * TINV);
    }
  }
#pragma unroll
  for (int j = 0; j < 32; ++j) {
    if (!((pmask >> j) & 1u)) sneg += __expf(va[j] * TINV - mneg);
  }
  int nc = __popc(qm);
#pragma unroll
  for (int o = 32; o; o >>= 1) {
    const float mo = __shfl_down(mneg, o), so = __shfl_down(sneg, o);
    const float M = fmaxf(mneg, mo);
    sneg = sneg * __expf(mneg - M) + so * __expf(mo - M);
    mneg = M;
    vmin = fminf(vmin, __shfl_down(vmin, o));
    vmax = fmaxf(vmax, __shfl_down(vmax, o));
    nc += __shfl_down(nc, o);
  }
  if (lane == 0) {
    redm[wid] = mneg; reds[wid] = sneg; redmin[wid] = vmin; redmax[wid] = vmax;
    redn[wid] = nc;
  }

  const int np = __popc(pmask);
  unsigned incl = (unsigned)np;
#pragma unroll
  for (int o = 1; o < 64; o <<= 1) {
    const unsigned t = __shfl_up(incl, o);
    if (lane >= o) incl += t;
  }
  const unsigned excl = incl - (unsigned)np;
  const unsigned wtot = __shfl(incl, 63);
  unsigned wbase = 0u;
  if (lane == 63) wbase = (unsigned)atomicAdd(&s_cnt, (int)wtot);
  wbase = __shfl(wbase, 63);
  const int ofs = (int)(wbase + excl);
  if (ofs + np <= PCAP) {
#pragma unroll
    for (int j = 0; j < 32; ++j) {
      if ((pmask >> j) & 1u)
        poskeys[ofs + __popc(pmask & ((1u << j) - 1u))] = f2key(va[j]);
    }
  }
  __syncthreads();

  const int P = s_cnt;
  if (tid == 0) {
    float M = redm[0], S = 0.f;
    float mn = redmin[0], mx = redmax[0];
    int n1 = 0;
    for (int w = 1; w < 16; ++w) {
      M = fmaxf(M, redm[w]);
      mn = fminf(mn, redmin[w]);
      mx = fmaxf(mx, redmax[w]);
    }
    for (int w = 0; w < 16; ++w) { S += reds[w] * __expf(redm[w] - M); n1 += redn[w]; }
    s_logE = M + logf(S);
    s_vmin = mn;
    s_vmax = mx;
    int mm = 0x7fffffff;
    if (has01 & 1) mm = min(mm, KQ - n1);
    if (has01 & 2) mm = min(mm, n1);
    s_m = mm;
  }
  if (tid < ((4 - (P & 3)) & 3)) poskeys[P + tid] = 0u;
  for (int i = tid; i < NB + 1; i += 1024) hist[i] = 0u;
  __syncthreads();

  const float cE = s_logE;
  const int m = s_m;
  const float vmn = s_vmin;
  const float scale = (float)NB * (1.0f - 1e-6f) / fmaxf(s_vmax - vmn, 1e-30f);
  auto key2bin = [&](unsigned k) {
    int bn = (int)((key2f(k) - vmn) * scale);
    return bn < 0 ? 0 : (bn > NB - 1 ? NB - 1 : bn);
  };

  for (int i = tid; i < P; i += 1024) atomicAdd(&hist[key2bin(poskeys[i])], 1u);
  __syncthreads();

  const int t4 = tid << 2;
  const unsigned h0 = hist[t4], h1 = hist[t4 + 1], h2 = hist[t4 + 2], h3 = hist[t4 + 3];
  const unsigned part = h0 + h1 + h2 + h3;
  unsigned sinc = part;
#pragma unroll
  for (int o = 1; o < 64; o <<= 1) {
    const unsigned t = __shfl_up(sinc, o);
    if (lane >= o) sinc += t;
  }
  if (lane == 63) wsum[wid] = sinc;
  __syncthreads();
  unsigned woff = 0;
  for (int w = 0; w < wid; ++w) woff += wsum[w];
  const unsigned exb = woff + sinc - part;
  hist[t4] = exb; hist[t4 + 1] = exb + h0; hist[t4 + 2] = exb + h0 + h1;
  hist[t4 + 3] = exb + h0 + h1 + h2;
  if (tid == 1023) hist[NB] = exb + part;
  __syncthreads();

  const int rt0 = 25, rt1 = m - 25, rt2 = m;
  const unsigned idx0 = (unsigned)(P - rt0), idx1 = (unsigned)(P - rt1), idx2 = (unsigned)(P - rt2);
#pragma unroll
  for (int i = 0; i < 4; ++i) {
    const int bb = t4 + i;
    const unsigned pb = hist[bb], pb1 = hist[bb + 1];
    if (pb <= idx0 && idx0 < pb1) { abin[0] = bb; acnt[0] = P - (int)pb1; }
    if (pb <= idx1 && idx1 < pb1) { abin[1] = bb; acnt[1] = P - (int)pb1; }
    if (pb <= idx2 && idx2 < pb1) { abin[2] = bb; acnt[2] = P - (int)pb1; }
  }
  __syncthreads();

  const int tb0 = abin[0], tb1 = abin[1], tb2 = abin[2];
  for (int i = tid; i < P; i += 1024) {
    const unsigned k = poskeys[i];
    const int bn = key2bin(k);
    if (bn == tb0) { const int p = atomicAdd(&candn[0], 1); if (p < CCAP) cand[0][p] = k; }
    if (bn == tb1) { const int p = atomicAdd(&candn[1], 1); if (p < CCAP) cand[1][p] = k; }
    if (bn == tb2) { const int p = atomicAdd(&candn[2], 1); if (p < CCAP) cand[2][p] = k; }
  }
  __syncthreads();

  if (wid < 3) {
    const int j = wid;
    const int rts[3] = {rt0, rt1, rt2};
    const int cnt = candn[j] < CCAP ? candn[j] : CCAP;
    const int rr = rts[j] - acnt[j];
    for (int i = lane; i < cnt; i += 64) {
      const unsigned k = cand[j][i];
      int gt = 0, eq = 0;
      for (int q = 0; q < cnt; ++q) {
        const unsigned kq = cand[j][q];
        gt += (kq > k);
        eq += (kq == k);
      }
      if (gt < rr && rr <= gt + eq) akey[j] = k;
    }
  }
  __syncthreads();

  const unsigned a0 = akey[0], a1 = akey[1], a2 = akey[2];
  const int P4c = (P + 3) >> 2;
  const uint4* __restrict__ pk4 = reinterpret_cast<const uint4*>(poskeys);

  float s0 = 0.f, sm = 0.f;
  unsigned q0c = 0, q1c = 0, q2c = 0;
  for (int i = tid; i < P4c; i += 1024) {
    const uint4 kv = pk4[i];
    const unsigned ks[4] = {kv.x, kv.y, kv.z, kv.w};
#pragma unroll
    for (int j = 0; j < 4; ++j) {
      const unsigned k = ks[j];
      if (k > a2) {
        ++q2c;
        const bool top = (k > a0), mid = (k <= a1);
        if (k > a1) ++q1c;
        if (top) ++q0c;
        if (top || mid) {
          const float a = key2f(k) * TINV;
          const float d = cE - a;
          const float fv = fmaxf(d, 0.f) + log1pf(__expf(-fabsf(d)));
          if (top) s0 += fv;
          if (mid) sm += fv;
        }
      }
    }
  }
  unsigned long long pc = (unsigned long long)q0c |
                          ((unsigned long long)q1c << 20) |
                          ((unsigned long long)q2c << 40);
#pragma unroll
  for (int o = 32; o; o >>= 1) {
    s0 += __shfl_down(s0, o);
    sm += __shfl_down(sm, o);
    pc += shfl_down_u64(pc, o);
  }
  if (lane == 0) {
    atomicAdd(&gs0, s0);
    atomicAdd(&gsm, sm);
    atomicAdd(&accg, pc);
  }
  __syncthreads();
  if (tid == 0) {
    const unsigned long long t = accg;
    const float C0 = (float)(unsigned)(t & 0xFFFFFu);
    const float C1 = (float)(unsigned)((t >> 20) & 0xFFFFFu);
    const float C2 = (float)(unsigned)((t >> 40) & 0xFFFFFu);
    auto fval = [&](unsigned kk) {
      const float a = key2f(kk) * TINV;
      const float d = cE - a;
      return fmaxf(d, 0.f) + log1pf(__expf(-fabsf(d)));
    };
    const float f0 = fval(a0), f1 = fval(a1), f2 = fval(a2);
    const float top25 = gs0 + (25.0f - C0) * f0;
    const float mid = gsm + ((float)m - C2) * f2 - ((float)(m - 25) - C1) * f1;
    atomicAdd(out, 0.1f * (top25 + mid) * (1.0f / 6400.0f));
  }
}

extern "C" void kernel_launch(void* const* d_in, const int* in_sizes, int n_in,
                              void* d_out, int out_size, void* d_ws, size_t ws_size,
                              hipStream_t stream) {
  const float* pooled = (const float*)d_in[0];
  const int* labels = (const int*)d_in[1];
  const float* fq = (const float*)d_in[2];
  const int* lq = (const int*)d_in[3];
  const float* cls_dw = (const float*)d_in[4];
  const float* cls_db = (const float*)d_in[5];
  const float* cls_ow = (const float*)d_in[6];
  const float* cls_ob = (const float*)d_in[7];
  const float* con_dw = (const float*)d_in[8];
  const float* con_db = (const float*)d_in[9];
  const float* con_ow = (const float*)d_in[10];
  const float* con_ob = (const float*)d_in[11];
  float* out = (float*)d_out;

  float* ws = (float*)d_ws;
  float* H1 = ws;                                         // 128*768 f32
  float* H2 = ws + 98304;                                 // 128*768 f32
  float* Y = ws + 2 * 98304;                              // 128*768 f32
  unsigned short* qh = (unsigned short*)(ws + 3 * 98304); // 128*768 bf16
  float* C = ws + 4 * 98304;                              // 128*32768 f32

  dense_pair<<<dim3(24, 4, 2), 256, 0, stream>>>(pooled, cls_dw, cls_db, H1,
                                                 con_dw, con_db, H2, out);
  gemm_bias<<<dim3(24, 4), 256, 0, stream>>>(H2, con_ow, con_ob, Y);
  aux_kernel<<<256, 256, 0, stream>>>(Y, qh, H1, cls_ow, cls_ob, labels, out);
  cos_gemm_mfma<<<512, 256, 0, stream>>>(qh, fq, C);
  select_kernel<<<128, 1024, 0, stream>>>(C, labels, lq, out);
}

// Round 11
// 105.982 us; speedup vs baseline: 1.3940x; 1.0056x over previous
//
#include <hip/hip_runtime.h>
#include <math.h>

#define BB 128
#define HH 768
#define KQ 32768
#define PCAP 18432  // max positives per row staged in LDS
#define NB 4096     // histogram bins
#define CCAP 512    // candidate cap per target bin

constexpr float TINV = 1.0f / 0.07f;

typedef __attribute__((ext_vector_type(8))) short short8;
typedef __attribute__((ext_vector_type(4))) float f32x4;
typedef __attribute__((address_space(3))) void lds_void;
typedef const __attribute__((address_space(1))) void gbl_void;

__device__ __forceinline__ unsigned short f2bf(float f) {
  unsigned u = __float_as_uint(f);
  unsigned r = u + 0x7FFFu + ((u >> 16) & 1u);  // RNE
  return (unsigned short)(r >> 16);
}
__device__ __forceinline__ unsigned f2key(float f) {
  unsigned u = __float_as_uint(f);
  return u ^ (unsigned)(((int)u >> 31) | 0x80000000);
}
__device__ __forceinline__ float key2f(unsigned k) {
  unsigned u = (k & 0x80000000u) ? (k & 0x7FFFFFFFu) : ~k;
  return __uint_as_float(u);
}
__device__ __forceinline__ unsigned long long shfl_down_u64(unsigned long long v, int o) {
  unsigned lo = (unsigned)v, hi = (unsigned)(v >> 32);
  lo = __shfl_down(lo, o);
  hi = __shfl_down(hi, o);
  return ((unsigned long long)hi << 32) | lo;
}
__device__ __forceinline__ void gl16(const unsigned short* g, unsigned short* l) {
  __builtin_amdgcn_global_load_lds((gbl_void*)g, (lds_void*)l, 16, 0, 0);
}

// C = tanh(A @ W{0,1} + b{0,1}); z picks head. Also zeroes out[0] (block 0).
__global__ __launch_bounds__(256) void dense_pair(
    const float* __restrict__ A, const float* __restrict__ W0,
    const float* __restrict__ b0, float* __restrict__ C0,
    const float* __restrict__ W1, const float* __restrict__ b1,
    float* __restrict__ C1, float* __restrict__ out) {
  if (blockIdx.x == 0 && blockIdx.y == 0 && blockIdx.z == 0 && threadIdx.x == 0)
    out[0] = 0.0f;
  const float* W = blockIdx.z ? W1 : W0;
  const float* bias = blockIdx.z ? b1 : b0;
  float* Cout = blockIdx.z ? C1 : C0;
  __shared__ float As[32][33];
  __shared__ float Ws[32][36];
  const int n0 = blockIdx.x * 32;
  const int m0 = blockIdx.y * 32;
  const int tid = threadIdx.x;
  const int tn = tid & 15, tm = tid >> 4;
  const int r = tid >> 3, c = (tid & 7) << 2;
  float acc[2][2] = {};
  for (int k0 = 0; k0 < HH; k0 += 32) {
    const float4 a4 = *reinterpret_cast<const float4*>(A + (size_t)(m0 + r) * HH + k0 + c);
    As[c + 0][r] = a4.x; As[c + 1][r] = a4.y; As[c + 2][r] = a4.z; As[c + 3][r] = a4.w;
    const float4 w4 = *reinterpret_cast<const float4*>(W + (size_t)(k0 + r) * HH + n0 + c);
    *reinterpret_cast<float4*>(&Ws[r][c]) = w4;
    __syncthreads();
#pragma unroll
    for (int kk = 0; kk < 32; ++kk) {
      const float a0 = As[kk][tm * 2], a1 = As[kk][tm * 2 + 1];
      const float w0 = Ws[kk][tn * 2], w1 = Ws[kk][tn * 2 + 1];
      acc[0][0] = fmaf(a0, w0, acc[0][0]); acc[0][1] = fmaf(a0, w1, acc[0][1]);
      acc[1][0] = fmaf(a1, w0, acc[1][0]); acc[1][1] = fmaf(a1, w1, acc[1][1]);
    }
    __syncthreads();
  }
  const float b0v = bias[n0 + tn * 2], b1v = bias[n0 + tn * 2 + 1];
#pragma unroll
  for (int i = 0; i < 2; ++i) {
    float* dst = Cout + (size_t)(m0 + tm * 2 + i) * HH + n0 + tn * 2;
    dst[0] = tanhf(acc[i][0] + b0v);
    dst[1] = tanhf(acc[i][1] + b1v);
  }
}

// C = A @ W + b (no act). BM=BN=32, BK=32.
__global__ __launch_bounds__(256) void gemm_bias(
    const float* __restrict__ A, const float* __restrict__ W,
    const float* __restrict__ bias, float* __restrict__ Cout) {
  __shared__ float As[32][33];
  __shared__ float Ws[32][36];
  const int n0 = blockIdx.x * 32;
  const int m0 = blockIdx.y * 32;
  const int tid = threadIdx.x;
  const int tn = tid & 15, tm = tid >> 4;
  const int r = tid >> 3, c = (tid & 7) << 2;
  float acc[2][2] = {};
  for (int k0 = 0; k0 < HH; k0 += 32) {
    const float4 a4 = *reinterpret_cast<const float4*>(A + (size_t)(m0 + r) * HH + k0 + c);
    As[c + 0][r] = a4.x; As[c + 1][r] = a4.y; As[c + 2][r] = a4.z; As[c + 3][r] = a4.w;
    const float4 w4 = *reinterpret_cast<const float4*>(W + (size_t)(k0 + r) * HH + n0 + c);
    *reinterpret_cast<float4*>(&Ws[r][c]) = w4;
    __syncthreads();
#pragma unroll
    for (int kk = 0; kk < 32; ++kk) {
      const float a0 = As[kk][tm * 2], a1 = As[kk][tm * 2 + 1];
      const float w0 = Ws[kk][tn * 2], w1 = Ws[kk][tn * 2 + 1];
      acc[0][0] = fmaf(a0, w0, acc[0][0]); acc[0][1] = fmaf(a0, w1, acc[0][1]);
      acc[1][0] = fmaf(a1, w0, acc[1][0]); acc[1][1] = fmaf(a1, w1, acc[1][1]);
    }
    __syncthreads();
  }
  const float b0v = bias[n0 + tn * 2], b1v = bias[n0 + tn * 2 + 1];
#pragma unroll
  for (int i = 0; i < 2; ++i) {
    float* dst = Cout + (size_t)(m0 + tm * 2 + i) * HH + n0 + tn * 2;
    dst[0] = acc[i][0] + b0v;
    dst[1] = acc[i][1] + b1v;
  }
}

// cos GEMM v11: v10 (BM=128 x BN=64, 4 waves, grid=512, 4 blocks/CU, 64k
// chunks, counted-vmcnt) + sched_barrier(0) fences pinning VMEM issue order
// so the counted waits are correct by construction:
//   [gl16 x4] | fence | [B-loads x4 + MFMA] | fence | vmcnt(N) + s_barrier.
__global__ __launch_bounds__(256, 4) void cos_gemm_mfma(
    const unsigned short* __restrict__ qh, const float* __restrict__ FQ,
    float* __restrict__ C) {
  __shared__ unsigned short Abuf[2][128 * 64];  // 2 x 16 KB
  const int tid = threadIdx.x;
  const int lane = tid & 63, wid = tid >> 6;  // 4 waves
  const int bid = blockIdx.x;
  const int swz = (bid & 7) * 64 + (bid >> 3);  // bijective XCD swizzle (512%8==0)
  const int q0 = swz * 64;
  const int a_r = lane & 15, a_kq = lane >> 4;

  // A staging: issue j of wave w covers rows (w*4+j)*8 .. +8 (8 rows x 64k).
  // Lane l -> row +(l>>3), slot l&7 holds source k-group (l&7)^(row&7).
  int asrc[4], adst[4];
#pragma unroll
  for (int j = 0; j < 4; ++j) {
    const int rr = (wid * 4 + j) * 8 + (lane >> 3);
    const int kb = (lane & 7) ^ (rr & 7);
    asrc[j] = rr * HH + kb * 8;
    adst[j] = (wid * 4 + j) * 512;  // halfword units (8 rows x 64)
  }
  // B: fq row = q0 + wid*16 + a_r; k = s*32 + a_kq*8
  const float* __restrict__ bptr = FQ + (size_t)(q0 + wid * 16 + a_r) * HH + a_kq * 8;
  // compute-side A slot within 64k chunk: slot = (st*4 + a_kq) ^ (a_r & 7)
  int aslot[2];
#pragma unroll
  for (int st = 0; st < 2; ++st) aslot[st] = (((st * 4 + a_kq) ^ (a_r & 7)) << 3);

  f32x4 acc[8];
#pragma unroll
  for (int m = 0; m < 8; ++m) acc[m] = (f32x4){0.f, 0.f, 0.f, 0.f};

  // prologue: stage chunk 0 (4 gl16) | fence | preload B s=0..3 | vmcnt(8)
#pragma unroll
  for (int j = 0; j < 4; ++j) gl16(qh + asrc[j], &Abuf[0][adst[j]]);
  __builtin_amdgcn_sched_barrier(0);  // pin: gl16 issue before B preloads
  float4 bv[4][2];
#pragma unroll
  for (int p = 0; p < 4; ++p) {
    bv[p][0] = *reinterpret_cast<const float4*>(bptr + p * 32);
    bv[p][1] = *reinterpret_cast<const float4*>(bptr + p * 32 + 4);
  }
  __builtin_amdgcn_sched_barrier(0);
  asm volatile("s_waitcnt vmcnt(8)" ::: "memory");  // oldest 4 = gl16 retired
  __builtin_amdgcn_s_barrier();
  __builtin_amdgcn_sched_barrier(0);

#pragma unroll
  for (int c = 0; c < 12; ++c) {
    if (c < 11) {
#pragma unroll
      for (int j = 0; j < 4; ++j)
        gl16(qh + (c + 1) * 64 + asrc[j], &Abuf[(c + 1) & 1][adst[j]]);
    }
    __builtin_amdgcn_sched_barrier(0);  // pin: gl16 before this chunk's B loads
    const unsigned short* __restrict__ Ab = Abuf[c & 1];
#pragma unroll
    for (int st = 0; st < 2; ++st) {
      const int s = c * 2 + st;
      const float4 v0 = bv[s & 3][0], v1 = bv[s & 3][1];
      if (s + 4 < 24) {
        bv[s & 3][0] = *reinterpret_cast<const float4*>(bptr + (s + 4) * 32);
        bv[s & 3][1] = *reinterpret_cast<const float4*>(bptr + (s + 4) * 32 + 4);
      }
      short8 bb;
      bb[0] = (short)f2bf(v0.x); bb[1] = (short)f2bf(v0.y);
      bb[2] = (short)f2bf(v0.z); bb[3] = (short)f2bf(v0.w);
      bb[4] = (short)f2bf(v1.x); bb[5] = (short)f2bf(v1.y);
      bb[6] = (short)f2bf(v1.z); bb[7] = (short)f2bf(v1.w);
      const int sl = aslot[st];
#pragma unroll
      for (int m = 0; m < 8; ++m) {
        const short8 aa =
            *reinterpret_cast<const short8*>(&Ab[(m * 16 + a_r) * 64 + sl]);
        acc[m] = __builtin_amdgcn_mfma_f32_16x16x32_bf16(aa, bb, acc[m], 0, 0, 0);
      }
    }
    if (c < 11) {
      __builtin_amdgcn_sched_barrier(0);  // pin: B loads stay above the wait
      // chunks 0..9: newest 4 outstanding = this chunk's 4 B loads ->
      // vmcnt(4) retires gl16(c+1) (and older B), keeps B in flight.
      // chunk 10: no B loads issued in-chunk -> drain to 0 before last chunk.
      if (c < 10) asm volatile("s_waitcnt vmcnt(4)" ::: "memory");
      else        asm volatile("s_waitcnt vmcnt(0)" ::: "memory");
      __builtin_amdgcn_s_barrier();
      __builtin_amdgcn_sched_barrier(0);
    }
  }

  const int ccol = q0 + wid * 16 + a_r;
#pragma unroll
  for (int m = 0; m < 8; ++m)
#pragma unroll
    for (int r = 0; r < 4; ++r)
      C[(size_t)(m * 16 + a_kq * 4 + r) * KQ + ccol] = acc[m][r];
}

// Fused: blocks 0..127 l2norm(Y)->qh bf16; blocks 128..255 cls CE loss.
__global__ __launch_bounds__(256) void aux_kernel(
    const float* __restrict__ Y, unsigned short* __restrict__ qh,
    const float* __restrict__ H1, const float* __restrict__ W2,
    const float* __restrict__ b2, const int* __restrict__ labels,
    float* __restrict__ out) {
  const int tid = threadIdx.x;
  const int lane = tid & 63, wid = tid >> 6;
  __shared__ float sh0[4], sh1[4];
  __shared__ float snorm;
  if (blockIdx.x < 128) {
    const int b = blockIdx.x;
    float ss = 0.f;
    for (int h = tid; h < HH; h += 256) {
      const float v = Y[(size_t)b * HH + h];
      ss = fmaf(v, v, ss);
    }
    for (int o = 32; o; o >>= 1) ss += __shfl_down(ss, o);
    if (lane == 0) sh0[wid] = ss;
    __syncthreads();
    if (tid == 0) snorm = 1.0f / sqrtf(sh0[0] + sh0[1] + sh0[2] + sh0[3]);
    __syncthreads();
    const float rs = snorm;
    for (int h = tid; h < HH; h += 256)
      qh[(size_t)b * HH + h] = f2bf(Y[(size_t)b * HH + h] * rs);
  } else {
    const int b = blockIdx.x - 128;
    float p0 = 0.f, p1 = 0.f;
    for (int h = tid; h < HH; h += 256) {
      const float v = H1[(size_t)b * HH + h];
      p0 = fmaf(v, W2[h * 2 + 0], p0);
      p1 = fmaf(v, W2[h * 2 + 1], p1);
    }
    for (int o = 32; o; o >>= 1) {
      p0 += __shfl_down(p0, o);
      p1 += __shfl_down(p1, o);
    }
    if (lane == 0) { sh0[wid] = p0; sh1[wid] = p1; }
    __syncthreads();
    if (tid == 0) {
      const float l0 = sh0[0] + sh0[1] + sh0[2] + sh0[3] + b2[0];
      const float l1 = sh1[0] + sh1[1] + sh1[2] + sh1[3] + b2[1];
      const float mx = fmaxf(l0, l1), mn = fminf(l0, l1);
      const float lse = mx + log1pf(__expf(mn - mx));
      const float ce = lse - (labels[b] ? l1 : l0);
      atomicAdd(out, 0.9f * ce * (1.0f / 128.0f));
    }
  }
}

// Self-contained select: builds qmask/m from lq+labels, then pass A (neg-lse +
// pos compaction), histogram radix-select for ranks {25,m-25,m}, gather.
__global__ __launch_bounds__(1024) void select_kernel(
    const float* __restrict__ Cm, const int* __restrict__ labels,
    const int* __restrict__ lq, float* __restrict__ out) {
  const int b = blockIdx.x;
  const int tid = threadIdx.x;
  const int lane = tid & 63, wid = tid >> 6;
  const float* __restrict__ row = Cm + (size_t)b * KQ;
  const int lab = labels[b];

  __shared__ __align__(16) unsigned poskeys[PCAP];
  __shared__ unsigned hist[NB + 1];
  __shared__ unsigned cand[3][CCAP];
  __shared__ int candn[3];
  __shared__ float redm[16], reds[16], redmin[16], redmax[16];
  __shared__ int redn[16];
  __shared__ unsigned wsum[16];
  __shared__ int abin[3], acnt[3];
  __shared__ unsigned akey[3];
  __shared__ unsigned long long accg;
  __shared__ float gs0, gsm, s_logE, s_vmin, s_vmax;
  __shared__ int s_cnt, s_m, has01;

  if (tid == 0) { s_cnt = 0; gs0 = 0.f; gsm = 0.f; accg = 0ull; has01 = 0; }
  if (tid < 3) candn[tid] = 0;
  __syncthreads();

  // ---------- Pass A ----------
  const int base = tid << 5;
  unsigned qm = 0u;
  {
    const int4* __restrict__ lq4 = reinterpret_cast<const int4*>(lq + base);
#pragma unroll
    for (int u = 0; u < 8; ++u) {
      const int4 q = lq4[u];
      qm |= (unsigned)(q.x != 0) << (u * 4 + 0);
      qm |= (unsigned)(q.y != 0) << (u * 4 + 1);
      qm |= (unsigned)(q.z != 0) << (u * 4 + 2);
      qm |= (unsigned)(q.w != 0) << (u * 4 + 3);
    }
  }
  if (tid < BB) atomicOr(&has01, 1 << labels[tid]);
  const unsigned pmask = lab ? qm : ~qm;
  float va[32];
#pragma unroll
  for (int u = 0; u < 8; ++u) {
    const float4 v = *reinterpret_cast<const float4*>(row + base + (u << 2));
    va[(u << 2) + 0] = v.x; va[(u << 2) + 1] = v.y;
    va[(u << 2) + 2] = v.z; va[(u << 2) + 3] = v.w;
  }
  float mneg = -3.0e38f, sneg = 0.f, vmin = 3.0e38f, vmax = -3.0e38f;
#pragma unroll
  for (int j = 0; j < 32; ++j) {
    if ((pmask >> j) & 1u) {
      vmin = fminf(vmin, va[j]);
      vmax = fmaxf(vmax, va[j]);
    } else {
      mneg = fmaxf(mneg, va[j] * TINV);
    }
  }
#pragma unroll
  for (int j = 0; j < 32; ++j) {
    if (!((pmask >> j) & 1u)) sneg += __expf(va[j] * TINV - mneg);
  }
  int nc = __popc(qm);
#pragma unroll
  for (int o = 32; o; o >>= 1) {
    const float mo = __shfl_down(mneg, o), so = __shfl_down(sneg, o);
    const float M = fmaxf(mneg, mo);
    sneg = sneg * __expf(mneg - M) + so * __expf(mo - M);
    mneg = M;
    vmin = fminf(vmin, __shfl_down(vmin, o));
    vmax = fmaxf(vmax, __shfl_down(vmax, o));
    nc += __shfl_down(nc, o);
  }
  if (lane == 0) {
    redm[wid] = mneg; reds[wid] = sneg; redmin[wid] = vmin; redmax[wid] = vmax;
    redn[wid] = nc;
  }

  const int np = __popc(pmask);
  unsigned incl = (unsigned)np;
#pragma unroll
  for (int o = 1; o < 64; o <<= 1) {
    const unsigned t = __shfl_up(incl, o);
    if (lane >= o) incl += t;
  }
  const unsigned excl = incl - (unsigned)np;
  const unsigned wtot = __shfl(incl, 63);
  unsigned wbase = 0u;
  if (lane == 63) wbase = (unsigned)atomicAdd(&s_cnt, (int)wtot);
  wbase = __shfl(wbase, 63);
  const int ofs = (int)(wbase + excl);
  if (ofs + np <= PCAP) {
#pragma unroll
    for (int j = 0; j < 32; ++j) {
      if ((pmask >> j) & 1u)
        poskeys[ofs + __popc(pmask & ((1u << j) - 1u))] = f2key(va[j]);
    }
  }
  __syncthreads();

  const int P = s_cnt;
  if (tid == 0) {
    float M = redm[0], S = 0.f;
    float mn = redmin[0], mx = redmax[0];
    int n1 = 0;
    for (int w = 1; w < 16; ++w) {
      M = fmaxf(M, redm[w]);
      mn = fminf(mn, redmin[w]);
      mx = fmaxf(mx, redmax[w]);
    }
    for (int w = 0; w < 16; ++w) { S += reds[w] * __expf(redm[w] - M); n1 += redn[w]; }
    s_logE = M + logf(S);
    s_vmin = mn;
    s_vmax = mx;
    int mm = 0x7fffffff;
    if (has01 & 1) mm = min(mm, KQ - n1);
    if (has01 & 2) mm = min(mm, n1);
    s_m = mm;
  }
  if (tid < ((4 - (P & 3)) & 3)) poskeys[P + tid] = 0u;
  for (int i = tid; i < NB + 1; i += 1024) hist[i] = 0u;
  __syncthreads();

  const float cE = s_logE;
  const int m = s_m;
  const float vmn = s_vmin;
  const float scale = (float)NB * (1.0f - 1e-6f) / fmaxf(s_vmax - vmn, 1e-30f);
  auto key2bin = [&](unsigned k) {
    int bn = (int)((key2f(k) - vmn) * scale);
    return bn < 0 ? 0 : (bn > NB - 1 ? NB - 1 : bn);
  };

  for (int i = tid; i < P; i += 1024) atomicAdd(&hist[key2bin(poskeys[i])], 1u);
  __syncthreads();

  const int t4 = tid << 2;
  const unsigned h0 = hist[t4], h1 = hist[t4 + 1], h2 = hist[t4 + 2], h3 = hist[t4 + 3];
  const unsigned part = h0 + h1 + h2 + h3;
  unsigned sinc = part;
#pragma unroll
  for (int o = 1; o < 64; o <<= 1) {
    const unsigned t = __shfl_up(sinc, o);
    if (lane >= o) sinc += t;
  }
  if (lane == 63) wsum[wid] = sinc;
  __syncthreads();
  unsigned woff = 0;
  for (int w = 0; w < wid; ++w) woff += wsum[w];
  const unsigned exb = woff + sinc - part;
  hist[t4] = exb; hist[t4 + 1] = exb + h0; hist[t4 + 2] = exb + h0 + h1;
  hist[t4 + 3] = exb + h0 + h1 + h2;
  if (tid == 1023) hist[NB] = exb + part;
  __syncthreads();

  const int rt0 = 25, rt1 = m - 25, rt2 = m;
  const unsigned idx0 = (unsigned)(P - rt0), idx1 = (unsigned)(P - rt1), idx2 = (unsigned)(P - rt2);
#pragma unroll
  for (int i = 0; i < 4; ++i) {
    const int bb = t4 + i;
    const unsigned pb = hist[bb], pb1 = hist[bb + 1];
    if (pb <= idx0 && idx0 < pb1) { abin[0] = bb; acnt[0] = P - (int)pb1; }
    if (pb <= idx1 && idx1 < pb1) { abin[1] = bb; acnt[1] = P - (int)pb1; }
    if (pb <= idx2 && idx2 < pb1) { abin[2] = bb; acnt[2] = P - (int)pb1; }
  }
  __syncthreads();

  const int tb0 = abin[0], tb1 = abin[1], tb2 = abin[2];
  for (int i = tid; i < P; i += 1024) {
    const unsigned k = poskeys[i];
    const int bn = key2bin(k);
    if (bn == tb0) { const int p = atomicAdd(&candn[0], 1); if (p < CCAP) cand[0][p] = k; }
    if (bn == tb1) { const int p = atomicAdd(&candn[1], 1); if (p < CCAP) cand[1][p] = k; }
    if (bn == tb2) { const int p = atomicAdd(&candn[2], 1); if (p < CCAP) cand[2][p] = k; }
  }
  __syncthreads();

  if (wid < 3) {
    const int j = wid;
    const int rts[3] = {rt0, rt1, rt2};
    const int cnt = candn[j] < CCAP ? candn[j] : CCAP;
    const int rr = rts[j] - acnt[j];
    for (int i = lane; i < cnt; i += 64) {
      const unsigned k = cand[j][i];
      int gt = 0, eq = 0;
      for (int q = 0; q < cnt; ++q) {
        const unsigned kq = cand[j][q];
        gt += (kq > k);
        eq += (kq == k);
      }
      if (gt < rr && rr <= gt + eq) akey[j] = k;
    }
  }
  __syncthreads();

  const unsigned a0 = akey[0], a1 = akey[1], a2 = akey[2];
  const int P4c = (P + 3) >> 2;
  const uint4* __restrict__ pk4 = reinterpret_cast<const uint4*>(poskeys);

  float s0 = 0.f, sm = 0.f;
  unsigned q0c = 0, q1c = 0, q2c = 0;
  for (int i = tid; i < P4c; i += 1024) {
    const uint4 kv = pk4[i];
    const unsigned ks[4] = {kv.x, kv.y, kv.z, kv.w};
#pragma unroll
    for (int j = 0; j < 4; ++j) {
      const unsigned k = ks[j];
      if (k > a2) {
        ++q2c;
        const bool top = (k > a0), mid = (k <= a1);
        if (k > a1) ++q1c;
        if (top) ++q0c;
        if (top || mid) {
          const float a = key2f(k) * TINV;
          const float d = cE - a;
          const float fv = fmaxf(d, 0.f) + log1pf(__expf(-fabsf(d)));
          if (top) s0 += fv;
          if (mid) sm += fv;
        }
      }
    }
  }
  unsigned long long pc = (unsigned long long)q0c |
                          ((unsigned long long)q1c << 20) |
                          ((unsigned long long)q2c << 40);
#pragma unroll
  for (int o = 32; o; o >>= 1) {
    s0 += __shfl_down(s0, o);
    sm += __shfl_down(sm, o);
    pc += shfl_down_u64(pc, o);
  }
  if (lane == 0) {
    atomicAdd(&gs0, s0);
    atomicAdd(&gsm, sm);
    atomicAdd(&accg, pc);
  }
  __syncthreads();
  if (tid == 0) {
    const unsigned long long t = accg;
    const float C0 = (float)(unsigned)(t & 0xFFFFFu);
    const float C1 = (float)(unsigned)((t >> 20) & 0xFFFFFu);
    const float C2 = (float)(unsigned)((t >> 40) & 0xFFFFFu);
    auto fval = [&](unsigned kk) {
      const float a = key2f(kk) * TINV;
      const float d = cE - a;
      return fmaxf(d, 0.f) + log1pf(__expf(-fabsf(d)));
    };
    const float f0 = fval(a0), f1 = fval(a1), f2 = fval(a2);
    const float top25 = gs0 + (25.0f - C0) * f0;
    const float mid = gsm + ((float)m - C2) * f2 - ((float)(m - 25) - C1) * f1;
    atomicAdd(out, 0.1f * (top25 + mid) * (1.0f / 6400.0f));
  }
}

extern "C" void kernel_launch(void* const* d_in, const int* in_sizes, int n_in,
                              void* d_out, int out_size, void* d_ws, size_t ws_size,
                              hipStream_t stream) {
  const float* pooled = (const float*)d_in[0];
  const int* labels = (const int*)d_in[1];
  const float* fq = (const float*)d_in[2];
  const int* lq = (const int*)d_in[3];
  const float* cls_dw = (const float*)d_in[4];
  const float* cls_db = (const float*)d_in[5];
  const float* cls_ow = (const float*)d_in[6];
  const float* cls_ob = (const float*)d_in[7];
  const float* con_dw = (const float*)d_in[8];
  const float* con_db = (const float*)d_in[9];
  const float* con_ow = (const float*)d_in[10];
  const float* con_ob = (const float*)d_in[11];
  float* out = (float*)d_out;

  float* ws = (float*)d_ws;
  float* H1 = ws;                                         // 128*768 f32
  float* H2 = ws + 98304;                                 // 128*768 f32
  float* Y = ws + 2 * 98304;                              // 128*768 f32
  unsigned short* qh = (unsigned short*)(ws + 3 * 98304); // 128*768 bf16
  float* C = ws + 4 * 98304;                              // 128*32768 f32

  dense_pair<<<dim3(24, 4, 2), 256, 0, stream>>>(pooled, cls_dw, cls_db, H1,
                                                 con_dw, con_db, H2, out);
  gemm_bias<<<dim3(24, 4), 256, 0, stream>>>(H2, con_ow, con_ob, Y);
  aux_kernel<<<256, 256, 0, stream>>>(Y, qh, H1, cls_ow, cls_ob, labels, out);
  cos_gemm_mfma<<<512, 256, 0, stream>>>(qh, fq, C);
  select_kernel<<<128, 1024, 0, stream>>>(C, labels, lq, out);
}

// Round 12
// 101.952 us; speedup vs baseline: 1.4491x; 1.0395x over previous
//
#include <hip/hip_runtime.h>
#include <math.h>

#define BB 128
#define HH 768
#define KQ 32768
#define PCAP 18432  // max positives per row staged in LDS
#define NB 4096     // histogram bins
#define CCAP 512    // candidate cap per target bin

constexpr float TINV = 1.0f / 0.07f;

typedef __attribute__((ext_vector_type(8))) short short8;
typedef __attribute__((ext_vector_type(4))) float f32x4;
typedef __attribute__((address_space(3))) void lds_void;
typedef const __attribute__((address_space(1))) void gbl_void;

__device__ __forceinline__ unsigned short f2bf(float f) {
  unsigned u = __float_as_uint(f);
  unsigned r = u + 0x7FFFu + ((u >> 16) & 1u);  // RNE
  return (unsigned short)(r >> 16);
}
__device__ __forceinline__ float bf2f(unsigned short h) {
  return __uint_as_float(((unsigned)h) << 16);
}
__device__ __forceinline__ unsigned f2key(float f) {
  unsigned u = __float_as_uint(f);
  return u ^ (unsigned)(((int)u >> 31) | 0x80000000);
}
__device__ __forceinline__ float key2f(unsigned k) {
  unsigned u = (k & 0x80000000u) ? (k & 0x7FFFFFFFu) : ~k;
  return __uint_as_float(u);
}
__device__ __forceinline__ unsigned long long shfl_down_u64(unsigned long long v, int o) {
  unsigned lo = (unsigned)v, hi = (unsigned)(v >> 32);
  lo = __shfl_down(lo, o);
  hi = __shfl_down(hi, o);
  return ((unsigned long long)hi << 32) | lo;
}
__device__ __forceinline__ void gl16(const unsigned short* g, unsigned short* l) {
  __builtin_amdgcn_global_load_lds((gbl_void*)g, (lds_void*)l, 16, 0, 0);
}

// C = tanh(A @ W{0,1} + b{0,1}); z picks head. Also zeroes out[0] (block 0).
__global__ __launch_bounds__(256) void dense_pair(
    const float* __restrict__ A, const float* __restrict__ W0,
    const float* __restrict__ b0, float* __restrict__ C0,
    const float* __restrict__ W1, const float* __restrict__ b1,
    float* __restrict__ C1, float* __restrict__ out) {
  if (blockIdx.x == 0 && blockIdx.y == 0 && blockIdx.z == 0 && threadIdx.x == 0)
    out[0] = 0.0f;
  const float* W = blockIdx.z ? W1 : W0;
  const float* bias = blockIdx.z ? b1 : b0;
  float* Cout = blockIdx.z ? C1 : C0;
  __shared__ float As[32][33];
  __shared__ float Ws[32][36];
  const int n0 = blockIdx.x * 32;
  const int m0 = blockIdx.y * 32;
  const int tid = threadIdx.x;
  const int tn = tid & 15, tm = tid >> 4;
  const int r = tid >> 3, c = (tid & 7) << 2;
  float acc[2][2] = {};
  for (int k0 = 0; k0 < HH; k0 += 32) {
    const float4 a4 = *reinterpret_cast<const float4*>(A + (size_t)(m0 + r) * HH + k0 + c);
    As[c + 0][r] = a4.x; As[c + 1][r] = a4.y; As[c + 2][r] = a4.z; As[c + 3][r] = a4.w;
    const float4 w4 = *reinterpret_cast<const float4*>(W + (size_t)(k0 + r) * HH + n0 + c);
    *reinterpret_cast<float4*>(&Ws[r][c]) = w4;
    __syncthreads();
#pragma unroll
    for (int kk = 0; kk < 32; ++kk) {
      const float a0 = As[kk][tm * 2], a1 = As[kk][tm * 2 + 1];
      const float w0 = Ws[kk][tn * 2], w1 = Ws[kk][tn * 2 + 1];
      acc[0][0] = fmaf(a0, w0, acc[0][0]); acc[0][1] = fmaf(a0, w1, acc[0][1]);
      acc[1][0] = fmaf(a1, w0, acc[1][0]); acc[1][1] = fmaf(a1, w1, acc[1][1]);
    }
    __syncthreads();
  }
  const float b0v = bias[n0 + tn * 2], b1v = bias[n0 + tn * 2 + 1];
#pragma unroll
  for (int i = 0; i < 2; ++i) {
    float* dst = Cout + (size_t)(m0 + tm * 2 + i) * HH + n0 + tn * 2;
    dst[0] = tanhf(acc[i][0] + b0v);
    dst[1] = tanhf(acc[i][1] + b1v);
  }
}

// Fused: bid<96 -> Ybf16 = bf16(H2 @ W + bias) (UNNORMALIZED; select applies
// the row 1/||.||). bid>=96 -> cls CE loss for row (bid-96).
__global__ __launch_bounds__(256) void gemm_cls(
    const float* __restrict__ H2, const float* __restrict__ W,
    const float* __restrict__ bias, unsigned short* __restrict__ Yb,
    const float* __restrict__ H1, const float* __restrict__ W2,
    const float* __restrict__ b2, const int* __restrict__ labels,
    float* __restrict__ out) {
  __shared__ float As[32][33];
  __shared__ float Ws[32][36];
  __shared__ float sh0[4], sh1[4];
  const int bid = blockIdx.x;
  const int tid = threadIdx.x;
  const int lane = tid & 63, wid = tid >> 6;
  if (bid < 96) {
    const int n0 = (bid % 24) * 32;
    const int m0 = (bid / 24) * 32;
    const int tn = tid & 15, tm = tid >> 4;
    const int r = tid >> 3, c = (tid & 7) << 2;
    float acc[2][2] = {};
    for (int k0 = 0; k0 < HH; k0 += 32) {
      const float4 a4 = *reinterpret_cast<const float4*>(H2 + (size_t)(m0 + r) * HH + k0 + c);
      As[c + 0][r] = a4.x; As[c + 1][r] = a4.y; As[c + 2][r] = a4.z; As[c + 3][r] = a4.w;
      const float4 w4 = *reinterpret_cast<const float4*>(W + (size_t)(k0 + r) * HH + n0 + c);
      *reinterpret_cast<float4*>(&Ws[r][c]) = w4;
      __syncthreads();
#pragma unroll
      for (int kk = 0; kk < 32; ++kk) {
        const float a0 = As[kk][tm * 2], a1 = As[kk][tm * 2 + 1];
        const float w0 = Ws[kk][tn * 2], w1 = Ws[kk][tn * 2 + 1];
        acc[0][0] = fmaf(a0, w0, acc[0][0]); acc[0][1] = fmaf(a0, w1, acc[0][1]);
        acc[1][0] = fmaf(a1, w0, acc[1][0]); acc[1][1] = fmaf(a1, w1, acc[1][1]);
      }
      __syncthreads();
    }
    const float b0v = bias[n0 + tn * 2], b1v = bias[n0 + tn * 2 + 1];
#pragma unroll
    for (int i = 0; i < 2; ++i) {
      ushort2 o;
      o.x = f2bf(acc[i][0] + b0v);
      o.y = f2bf(acc[i][1] + b1v);
      *reinterpret_cast<ushort2*>(Yb + (size_t)(m0 + tm * 2 + i) * HH + n0 + tn * 2) = o;
    }
  } else {
    const int b = bid - 96;
    float p0 = 0.f, p1 = 0.f;
    for (int h = tid; h < HH; h += 256) {
      const float v = H1[(size_t)b * HH + h];
      p0 = fmaf(v, W2[h * 2 + 0], p0);
      p1 = fmaf(v, W2[h * 2 + 1], p1);
    }
    for (int o = 32; o; o >>= 1) {
      p0 += __shfl_down(p0, o);
      p1 += __shfl_down(p1, o);
    }
    if (lane == 0) { sh0[wid] = p0; sh1[wid] = p1; }
    __syncthreads();
    if (tid == 0) {
      const float l0 = sh0[0] + sh0[1] + sh0[2] + sh0[3] + b2[0];
      const float l1 = sh1[0] + sh1[1] + sh1[2] + sh1[3] + b2[1];
      const float mx = fmaxf(l0, l1), mn = fminf(l0, l1);
      const float lse = mx + log1pf(__expf(mn - mx));
      const float ce = lse - (labels[b] ? l1 : l0);
      atomicAdd(out, 0.9f * ce * (1.0f / 128.0f));
    }
  }
}

// cos GEMM v13: BM=128 x BN=64, 4 waves, grid=512, TRI-buffered LDS with gl16
// issued 2 chunks ahead of use -> the end-of-chunk vmcnt wait targets a gl16
// that is >=2 chunks old, so it never drains recent B-loads (in-order vmcnt).
// B register prefetch 8 steps deep. All VMEM clusters pinned by sched_barrier.
__global__ __launch_bounds__(256, 2) void cos_gemm_mfma(
    const unsigned short* __restrict__ qh, const float* __restrict__ FQ,
    float* __restrict__ C) {
  __shared__ unsigned short Abuf[3][128 * 64];  // 3 x 16 KB
  const int tid = threadIdx.x;
  const int lane = tid & 63, wid = tid >> 6;  // 4 waves
  const int bid = blockIdx.x;
  const int swz = (bid & 7) * 64 + (bid >> 3);  // bijective XCD swizzle (512%8==0)
  const int q0 = swz * 64;
  const int a_r = lane & 15, a_kq = lane >> 4;

  // A staging: issue j of wave w covers rows (w*4+j)*8..+8 of the 64k chunk.
  // Lane l -> row +(l>>3), slot l&7 holds source k-group (l&7)^(row&7).
  int asrc[4], adst[4];
#pragma unroll
  for (int j = 0; j < 4; ++j) {
    const int rr = (wid * 4 + j) * 8 + (lane >> 3);
    const int kb = (lane & 7) ^ (rr & 7);
    asrc[j] = rr * HH + kb * 8;
    adst[j] = (wid * 4 + j) * 512;  // halfword units (8 rows x 64)
  }
  // B: fq row = q0 + wid*16 + a_r; k = s*32 + a_kq*8
  const float* __restrict__ bptr = FQ + (size_t)(q0 + wid * 16 + a_r) * HH + a_kq * 8;
  // compute-side A slot within 64k chunk: slot = (st*4 + a_kq) ^ (a_r & 7)
  int aslot[2];
#pragma unroll
  for (int st = 0; st < 2; ++st) aslot[st] = (((st * 4 + a_kq) ^ (a_r & 7)) << 3);

  f32x4 acc[8];
#pragma unroll
  for (int m = 0; m < 8; ++m) acc[m] = (f32x4){0.f, 0.f, 0.f, 0.f};

  // prologue: G0 | G1 | B(steps 0..7, 16 loads) | vmcnt(20) -> buf0 ready
#pragma unroll
  for (int j = 0; j < 4; ++j) gl16(qh + asrc[j], &Abuf[0][adst[j]]);
  __builtin_amdgcn_sched_barrier(0);
#pragma unroll
  for (int j = 0; j < 4; ++j) gl16(qh + 64 + asrc[j], &Abuf[1][adst[j]]);
  __builtin_amdgcn_sched_barrier(0);
  float4 bv[8][2];
#pragma unroll
  for (int p = 0; p < 8; ++p) {
    bv[p][0] = *reinterpret_cast<const float4*>(bptr + p * 32);
    bv[p][1] = *reinterpret_cast<const float4*>(bptr + p * 32 + 4);
  }
  __builtin_amdgcn_sched_barrier(0);
  asm volatile("s_waitcnt vmcnt(20)" ::: "memory");  // G0 retired
  __builtin_amdgcn_s_barrier();
  __builtin_amdgcn_sched_barrier(0);

#pragma unroll
  for (int c = 0; c < 12; ++c) {
    if (c + 2 < 12) {
#pragma unroll
      for (int j = 0; j < 4; ++j)
        gl16(qh + (c + 2) * 64 + asrc[j], &Abuf[(c + 2) % 3][adst[j]]);
    }
    __builtin_amdgcn_sched_barrier(0);  // pin gl16 batch above B/MFMA region
    const unsigned short* __restrict__ Ab = Abuf[c % 3];
#pragma unroll
    for (int st = 0; st < 2; ++st) {
      const int s = c * 2 + st;
      const float4 v0 = bv[s & 7][0], v1 = bv[s & 7][1];
      if (s + 8 < 24) {
        bv[s & 7][0] = *reinterpret_cast<const float4*>(bptr + (s + 8) * 32);
        bv[s & 7][1] = *reinterpret_cast<const float4*>(bptr + (s + 8) * 32 + 4);
      }
      short8 bb;
      bb[0] = (short)f2bf(v0.x); bb[1] = (short)f2bf(v0.y);
      bb[2] = (short)f2bf(v0.z); bb[3] = (short)f2bf(v0.w);
      bb[4] = (short)f2bf(v1.x); bb[5] = (short)f2bf(v1.y);
      bb[6] = (short)f2bf(v1.z); bb[7] = (short)f2bf(v1.w);
      const int sl = aslot[st];
#pragma unroll
      for (int m = 0; m < 8; ++m) {
        const short8 aa =
            *reinterpret_cast<const short8*>(&Ab[(m * 16 + a_r) * 64 + sl]);
        acc[m] = __builtin_amdgcn_mfma_f32_16x16x32_bf16(aa, bb, acc[m], 0, 0, 0);
      }
    }
    if (c < 11) {
      __builtin_amdgcn_sched_barrier(0);  // pin B/MFMA region above the wait
      // Need buf(c+1) ready = gl16(c+1) retired. Ops issued AFTER gl16(c+1):
      //  c==0: 16 prologue B + G2(4) + B0(4) = 24
      //  1<=c<=7: B(c-1)(4) + G(c+2)(4) + B(c)(4) = 12
      //  c==8: B7(4) + G10(4) = 8   (no B from chunk 8 on)
      //  c==9: G11(4) = 4
      //  c==10: nothing newer = 0
      if (c == 0)      asm volatile("s_waitcnt vmcnt(24)" ::: "memory");
      else if (c <= 7) asm volatile("s_waitcnt vmcnt(12)" ::: "memory");
      else if (c == 8) asm volatile("s_waitcnt vmcnt(8)" ::: "memory");
      else if (c == 9) asm volatile("s_waitcnt vmcnt(4)" ::: "memory");
      else             asm volatile("s_waitcnt vmcnt(0)" ::: "memory");
      __builtin_amdgcn_s_barrier();
      __builtin_amdgcn_sched_barrier(0);
    }
  }

  const int ccol = q0 + wid * 16 + a_r;
#pragma unroll
  for (int m = 0; m < 8; ++m)
#pragma unroll
    for (int r = 0; r < 4; ++r)
      C[(size_t)(m * 16 + a_kq * 4 + r) * KQ + ccol] = acc[m][r];
}

// Self-contained select: builds qmask/m from lq+labels, row-scale rs from the
// bf16 Y row (scale commutes with the GEMM), then pass A (neg-lse + pos
// compaction), histogram radix-select for ranks {25,m-25,m}, gather.
__global__ __launch_bounds__(1024) void select_kernel(
    const float* __restrict__ Cm, const unsigned short* __restrict__ Yb,
    const int* __restrict__ labels, const int* __restrict__ lq,
    float* __restrict__ out) {
  const int b = blockIdx.x;
  const int tid = threadIdx.x;
  const int lane = tid & 63, wid = tid >> 6;
  const float* __restrict__ row = Cm + (size_t)b * KQ;
  const int lab = labels[b];

  __shared__ __align__(16) unsigned poskeys[PCAP];
  __shared__ unsigned hist[NB + 1];
  __shared__ unsigned cand[3][CCAP];
  __shared__ int candn[3];
  __shared__ float redm[16], reds[16], redmin[16], redmax[16];
  __shared__ int redn[16];
  __shared__ unsigned wsum[16];
  __shared__ int abin[3], acnt[3];
  __shared__ unsigned akey[3];
  __shared__ unsigned long long accg;
  __shared__ float gs0, gsm, s_logE, s_vmin, s_vmax, s_rs;
  __shared__ float ssq[2];
  __shared__ int s_cnt, s_m, has01;

  if (tid == 0) { s_cnt = 0; gs0 = 0.f; gsm = 0.f; accg = 0ull; has01 = 0; }
  if (tid < 3) candn[tid] = 0;

  // ---------- row scale rs = 1/||Yb[b]|| ----------
  float ssl = 0.f;
  if (tid < 96) {
    const short8 y8 =
        *reinterpret_cast<const short8*>(Yb + (size_t)b * HH + tid * 8);
#pragma unroll
    for (int e = 0; e < 8; ++e) {
      const float v = bf2f((unsigned short)y8[e]);
      ssl = fmaf(v, v, ssl);
    }
  }
#pragma unroll
  for (int o = 32; o; o >>= 1) ssl += __shfl_down(ssl, o);
  if (lane == 0 && wid < 2) ssq[wid] = ssl;
  __syncthreads();
  if (tid == 0) s_rs = rsqrtf(ssq[0] + ssq[1]);
  __syncthreads();
  const float rs = s_rs;

  // ---------- Pass A ----------
  const int base = tid << 5;
  unsigned qm = 0u;
  {
    const int4* __restrict__ lq4 = reinterpret_cast<const int4*>(lq + base);
#pragma unroll
    for (int u = 0; u < 8; ++u) {
      const int4 q = lq4[u];
      qm |= (unsigned)(q.x != 0) << (u * 4 + 0);
      qm |= (unsigned)(q.y != 0) << (u * 4 + 1);
      qm |= (unsigned)(q.z != 0) << (u * 4 + 2);
      qm |= (unsigned)(q.w != 0) << (u * 4 + 3);
    }
  }
  if (tid < BB) atomicOr(&has01, 1 << labels[tid]);
  const unsigned pmask = lab ? qm : ~qm;
  float va[32];
#pragma unroll
  for (int u = 0; u < 8; ++u) {
    const float4 v = *reinterpret_cast<const float4*>(row + base + (u << 2));
    va[(u << 2) + 0] = v.x * rs; va[(u << 2) + 1] = v.y * rs;
    va[(u << 2) + 2] = v.z * rs; va[(u << 2) + 3] = v.w * rs;
  }
  float mneg = -3.0e38f, sneg = 0.f, vmin = 3.0e38f, vmax = -3.0e38f;
#pragma unroll
  for (int j = 0; j < 32; ++j) {
    if ((pmask >> j) & 1u) {
      vmin = fminf(vmin, va[j]);
      vmax = fmaxf(vmax, va[j]);
    } else {
      mneg = fmaxf(mneg, va[j] * TINV);
    }
  }
#pragma unroll
  for (int j = 0; j < 32; ++j) {
    if (!((pmask >> j) & 1u)) sneg += __expf(va[j] * TINV - mneg);
  }
  int nc = __popc(qm);
#pragma unroll
  for (int o = 32; o; o >>= 1) {
    const float mo = __shfl_down(mneg, o), so = __shfl_down(sneg, o);
    const float M = fmaxf(mneg, mo);
    sneg = sneg * __expf(mneg - M) + so * __expf(mo - M);
    mneg = M;
    vmin = fminf(vmin, __shfl_down(vmin, o));
    vmax = fmaxf(vmax, __shfl_down(vmax, o));
    nc += __shfl_down(nc, o);
  }
  if (lane == 0) {
    redm[wid] = mneg; reds[wid] = sneg; redmin[wid] = vmin; redmax[wid] = vmax;
    redn[wid] = nc;
  }

  const int np = __popc(pmask);
  unsigned incl = (unsigned)np;
#pragma unroll
  for (int o = 1; o < 64; o <<= 1) {
    const unsigned t = __shfl_up(incl, o);
    if (lane >= o) incl += t;
  }
  const unsigned excl = incl - (unsigned)np;
  const unsigned wtot = __shfl(incl, 63);
  unsigned wbase = 0u;
  if (lane == 63) wbase = (unsigned)atomicAdd(&s_cnt, (int)wtot);
  wbase = __shfl(wbase, 63);
  const int ofs = (int)(wbase + excl);
  if (ofs + np <= PCAP) {
#pragma unroll
    for (int j = 0; j < 32; ++j) {
      if ((pmask >> j) & 1u)
        poskeys[ofs + __popc(pmask & ((1u << j) - 1u))] = f2key(va[j]);
    }
  }
  __syncthreads();

  const int P = s_cnt;
  if (tid == 0) {
    float M = redm[0], S = 0.f;
    float mn = redmin[0], mx = redmax[0];
    int n1 = 0;
    for (int w = 1; w < 16; ++w) {
      M = fmaxf(M, redm[w]);
      mn = fminf(mn, redmin[w]);
      mx = fmaxf(mx, redmax[w]);
    }
    for (int w = 0; w < 16; ++w) { S += reds[w] * __expf(redm[w] - M); n1 += redn[w]; }
    s_logE = M + logf(S);
    s_vmin = mn;
    s_vmax = mx;
    int mm = 0x7fffffff;
    if (has01 & 1) mm = min(mm, KQ - n1);
    if (has01 & 2) mm = min(mm, n1);
    s_m = mm;
  }
  if (tid < ((4 - (P & 3)) & 3)) poskeys[P + tid] = 0u;
  for (int i = tid; i < NB + 1; i += 1024) hist[i] = 0u;
  __syncthreads();

  const float cE = s_logE;
  const int m = s_m;
  const float vmn = s_vmin;
  const float scale = (float)NB * (1.0f - 1e-6f) / fmaxf(s_vmax - vmn, 1e-30f);
  auto key2bin = [&](unsigned k) {
    int bn = (int)((key2f(k) - vmn) * scale);
    return bn < 0 ? 0 : (bn > NB - 1 ? NB - 1 : bn);
  };

  for (int i = tid; i < P; i += 1024) atomicAdd(&hist[key2bin(poskeys[i])], 1u);
  __syncthreads();

  const int t4 = tid << 2;
  const unsigned h0 = hist[t4], h1 = hist[t4 + 1], h2 = hist[t4 + 2], h3 = hist[t4 + 3];
  const unsigned part = h0 + h1 + h2 + h3;
  unsigned sinc = part;
#pragma unroll
  for (int o = 1; o < 64; o <<= 1) {
    const unsigned t = __shfl_up(sinc, o);
    if (lane >= o) sinc += t;
  }
  if (lane == 63) wsum[wid] = sinc;
  __syncthreads();
  unsigned woff = 0;
  for (int w = 0; w < wid; ++w) woff += wsum[w];
  const unsigned exb = woff + sinc - part;
  hist[t4] = exb; hist[t4 + 1] = exb + h0; hist[t4 + 2] = exb + h0 + h1;
  hist[t4 + 3] = exb + h0 + h1 + h2;
  if (tid == 1023) hist[NB] = exb + part;
  __syncthreads();

  const int rt0 = 25, rt1 = m - 25, rt2 = m;
  const unsigned idx0 = (unsigned)(P - rt0), idx1 = (unsigned)(P - rt1), idx2 = (unsigned)(P - rt2);
#pragma unroll
  for (int i = 0; i < 4; ++i) {
    const int bb = t4 + i;
    const unsigned pb = hist[bb], pb1 = hist[bb + 1];
    if (pb <= idx0 && idx0 < pb1) { abin[0] = bb; acnt[0] = P - (int)pb1; }
    if (pb <= idx1 && idx1 < pb1) { abin[1] = bb; acnt[1] = P - (int)pb1; }
    if (pb <= idx2 && idx2 < pb1) { abin[2] = bb; acnt[2] = P - (int)pb1; }
  }
  __syncthreads();

  const int tb0 = abin[0], tb1 = abin[1], tb2 = abin[2];
  for (int i = tid; i < P; i += 1024) {
    const unsigned k = poskeys[i];
    const int bn = key2bin(k);
    if (bn == tb0) { const int p = atomicAdd(&candn[0], 1); if (p < CCAP) cand[0][p] = k; }
    if (bn == tb1) { const int p = atomicAdd(&candn[1], 1); if (p < CCAP) cand[1][p] = k; }
    if (bn == tb2) { const int p = atomicAdd(&candn[2], 1); if (p < CCAP) cand[2][p] = k; }
  }
  __syncthreads();

  if (wid < 3) {
    const int j = wid;
    const int rts[3] = {rt0, rt1, rt2};
    const int cnt = candn[j] < CCAP ? candn[j] : CCAP;
    const int rr = rts[j] - acnt[j];
    for (int i = lane; i < cnt; i += 64) {
      const unsigned k = cand[j][i];
      int gt = 0, eq = 0;
      for (int q = 0; q < cnt; ++q) {
        const unsigned kq = cand[j][q];
        gt += (kq > k);
        eq += (kq == k);
      }
      if (gt < rr && rr <= gt + eq) akey[j] = k;
    }
  }
  __syncthreads();

  const unsigned a0 = akey[0], a1 = akey[1], a2 = akey[2];
  const int P4c = (P + 3) >> 2;
  const uint4* __restrict__ pk4 = reinterpret_cast<const uint4*>(poskeys);

  float s0 = 0.f, sm = 0.f;
  unsigned q0c = 0, q1c = 0, q2c = 0;
  for (int i = tid; i < P4c; i += 1024) {
    const uint4 kv = pk4[i];
    const unsigned ks[4] = {kv.x, kv.y, kv.z, kv.w};
#pragma unroll
    for (int j = 0; j < 4; ++j) {
      const unsigned k = ks[j];
      if (k > a2) {
        ++q2c;
        const bool top = (k > a0), mid = (k <= a1);
        if (k > a1) ++q1c;
        if (top) ++q0c;
        if (top || mid) {
          const float a = key2f(k) * TINV;
          const float d = cE - a;
          const float fv = fmaxf(d, 0.f) + log1pf(__expf(-fabsf(d)));
          if (top) s0 += fv;
          if (mid) sm += fv;
        }
      }
    }
  }
  unsigned long long pc = (unsigned long long)q0c |
                          ((unsigned long long)q1c << 20) |
                          ((unsigned long long)q2c << 40);
#pragma unroll
  for (int o = 32; o; o >>= 1) {
    s0 += __shfl_down(s0, o);
    sm += __shfl_down(sm, o);
    pc += shfl_down_u64(pc, o);
  }
  if (lane == 0) {
    atomicAdd(&gs0, s0);
    atomicAdd(&gsm, sm);
    atomicAdd(&accg, pc);
  }
  __syncthreads();
  if (tid == 0) {
    const unsigned long long t = accg;
    const float C0 = (float)(unsigned)(t & 0xFFFFFu);
    const float C1 = (float)(unsigned)((t >> 20) & 0xFFFFFu);
    const float C2 = (float)(unsigned)((t >> 40) & 0xFFFFFu);
    auto fval = [&](unsigned kk) {
      const float a = key2f(kk) * TINV;
      const float d = cE - a;
      return fmaxf(d, 0.f) + log1pf(__expf(-fabsf(d)));
    };
    const float f0 = fval(a0), f1 = fval(a1), f2 = fval(a2);
    const float top25 = gs0 + (25.0f - C0) * f0;
    const float mid = gsm + ((float)m - C2) * f2 - ((float)(m - 25) - C1) * f1;
    atomicAdd(out, 0.1f * (top25 + mid) * (1.0f / 6400.0f));
  }
}

extern "C" void kernel_launch(void* const* d_in, const int* in_sizes, int n_in,
                              void* d_out, int out_size, void* d_ws, size_t ws_size,
                              hipStream_t stream) {
  const float* pooled = (const float*)d_in[0];
  const int* labels = (const int*)d_in[1];
  const float* fq = (const float*)d_in[2];
  const int* lq = (const int*)d_in[3];
  const float* cls_dw = (const float*)d_in[4];
  const float* cls_db = (const float*)d_in[5];
  const float* cls_ow = (const float*)d_in[6];
  const float* cls_ob = (const float*)d_in[7];
  const float* con_dw = (const float*)d_in[8];
  const float* con_db = (const float*)d_in[9];
  const float* con_ow = (const float*)d_in[10];
  const float* con_ob = (const float*)d_in[11];
  float* out = (float*)d_out;

  float* ws = (float*)d_ws;
  float* H1 = ws;                                         // 128*768 f32
  float* H2 = ws + 98304;                                 // 128*768 f32
  unsigned short* Yb = (unsigned short*)(ws + 2 * 98304); // 128*768 bf16
  float* C = ws + 4 * 98304;                              // 128*32768 f32

  dense_pair<<<dim3(24, 4, 2), 256, 0, stream>>>(pooled, cls_dw, cls_db, H1,
                                                 con_dw, con_db, H2, out);
  gemm_cls<<<224, 256, 0, stream>>>(H2, con_ow, con_ob, Yb,
                                    H1, cls_ow, cls_ob, labels, out);
  cos_gemm_mfma<<<512, 256, 0, stream>>>(Yb, fq, C);
  select_kernel<<<128, 1024, 0, stream>>>(C, Yb, labels, lq, out);
}